// Round 1
// baseline (1273.001 us; speedup 1.0000x reference)
//
#include <hip/hip_runtime.h>

typedef unsigned short u16;
typedef unsigned int   u32;

// ---------- bf16 helpers (manual, RNE) ----------
__device__ __forceinline__ u16 f2bf(float f) {
    u32 u = __float_as_uint(f);
    u += 0x7fffu + ((u >> 16) & 1u);
    return (u16)(u >> 16);
}
__device__ __forceinline__ float bf2f(u16 s) {
    return __uint_as_float(((u32)s) << 16);
}
__device__ __forceinline__ u32 pack2bf(float f0, float f1) {
    return (u32)f2bf(f0) | ((u32)f2bf(f1) << 16);
}

// =======================================================================
// K0: qkv = x @ w_qkv^T, but only q (o in [0,768)) and v (o in [1536,2304))
// A: [16384, 768] fp32, W: [2304, 768] fp32.
// Output layout: [bh=b*12+h][n][d] fp32 for both q and v.
// 128x128 tile, 256 threads, 8x8 microtile (split 4+4), BK=32.
// =======================================================================
__global__ __launch_bounds__(256)
void gemm_qkv(const float* __restrict__ A, const float* __restrict__ W,
              float* __restrict__ qbuf, float* __restrict__ vbuf)
{
    __shared__ float Ask[32][128];
    __shared__ float Bsk[32][128];
    const int m0  = blockIdx.x * 128;
    const int bj  = blockIdx.y;                       // 0..11
    const int ow0 = (bj < 6) ? bj * 128 : 1536 + (bj - 6) * 128;
    const int tid = threadIdx.x;
    const int tx = tid & 15, ty = tid >> 4;
    const int lr = tid >> 1;                          // 0..127
    const int lkb = (tid & 1) * 16;                   // 0 or 16
    float acc[8][8];
    #pragma unroll
    for (int i = 0; i < 8; ++i)
        #pragma unroll
        for (int j = 0; j < 8; ++j) acc[i][j] = 0.f;

    for (int k0 = 0; k0 < 768; k0 += 32) {
        #pragma unroll
        for (int q = 0; q < 4; ++q) {
            const int kk = lkb + q * 4;
            float4 av = *(const float4*)&A[(size_t)(m0 + lr) * 768 + k0 + kk];
            Ask[kk+0][lr] = av.x; Ask[kk+1][lr] = av.y;
            Ask[kk+2][lr] = av.z; Ask[kk+3][lr] = av.w;
            float4 wv = *(const float4*)&W[(size_t)(ow0 + lr) * 768 + k0 + kk];
            Bsk[kk+0][lr] = wv.x; Bsk[kk+1][lr] = wv.y;
            Bsk[kk+2][lr] = wv.z; Bsk[kk+3][lr] = wv.w;
        }
        __syncthreads();
        #pragma unroll 4
        for (int kk = 0; kk < 32; ++kk) {
            float4 a0 = *(const float4*)&Ask[kk][4*ty];
            float4 a1 = *(const float4*)&Ask[kk][64 + 4*ty];
            float4 b0 = *(const float4*)&Bsk[kk][4*tx];
            float4 b1 = *(const float4*)&Bsk[kk][64 + 4*tx];
            float a[8] = {a0.x,a0.y,a0.z,a0.w,a1.x,a1.y,a1.z,a1.w};
            float b[8] = {b0.x,b0.y,b0.z,b0.w,b1.x,b1.y,b1.z,b1.w};
            #pragma unroll
            for (int i = 0; i < 8; ++i)
                #pragma unroll
                for (int j = 0; j < 8; ++j)
                    acc[i][j] = fmaf(a[i], b[j], acc[i][j]);
        }
        __syncthreads();
    }
    float* buf = (bj < 6) ? qbuf : vbuf;
    const int obase = (bj % 6) * 128;
    #pragma unroll
    for (int rp = 0; rp < 2; ++rp)
        #pragma unroll
        for (int i = 0; i < 4; ++i) {
            const int m  = m0 + rp*64 + 4*ty + i;
            const int b_ = m >> 8, n_ = m & 255;
            #pragma unroll
            for (int cp = 0; cp < 2; ++cp) {
                const int ol = obase + cp*64 + 4*tx;  // 0..767, mult of 4
                const int h = ol >> 6, d = ol & 63;
                float4 o4 = make_float4(acc[rp*4+i][cp*4+0], acc[rp*4+i][cp*4+1],
                                        acc[rp*4+i][cp*4+2], acc[rp*4+i][cp*4+3]);
                *(float4*)&buf[((((size_t)b_ * 12 + h) * 256 + n_) << 6) + d] = o4;
            }
        }
}

// =======================================================================
// K1: normalize q rows in place: q /= (||q|| + 1e-8). One wave per row.
// =======================================================================
__global__ __launch_bounds__(256)
void normalize_kernel(float* __restrict__ q)
{
    const int row = blockIdx.x * 4 + (threadIdx.x >> 6);
    const int d   = threadIdx.x & 63;
    const size_t idx = (size_t)row * 64 + d;
    const float val = q[idx];
    float s = val * val;
    #pragma unroll
    for (int off = 32; off > 0; off >>= 1) s += __shfl_xor(s, off);
    q[idx] = val / (sqrtf(s) + 1e-8f);
}

// =======================================================================
// K2: K[n][m] = exp(10*cos(n,m) - 10) off-diag, 0 on diag. bf16 out.
// One block per 128x128 tile of one (b,h). k-major LDS, 8x8 microtile.
// =======================================================================
__global__ __launch_bounds__(256)
void cost_kernel(const float* __restrict__ qn, u16* __restrict__ Kmat)
{
    __shared__ float Qak[64][128];
    __shared__ float Qbk[64][128];
    const int bh = blockIdx.y;
    const int tr = (blockIdx.x >> 1) * 128;
    const int tc = (blockIdx.x & 1) * 128;
    const float* qb = qn + (size_t)bh * (256 * 64);
    const int tid = threadIdx.x;
    const int tx = tid & 15, ty = tid >> 4;
    {
        const int r  = tid >> 1;            // 0..127
        const int kb = (tid & 1) * 32;
        #pragma unroll
        for (int qq = 0; qq < 8; ++qq) {
            const int k = kb + qq * 4;
            float4 a = *(const float4*)&qb[(size_t)(tr + r) * 64 + k];
            Qak[k+0][r] = a.x; Qak[k+1][r] = a.y; Qak[k+2][r] = a.z; Qak[k+3][r] = a.w;
            float4 b = *(const float4*)&qb[(size_t)(tc + r) * 64 + k];
            Qbk[k+0][r] = b.x; Qbk[k+1][r] = b.y; Qbk[k+2][r] = b.z; Qbk[k+3][r] = b.w;
        }
    }
    __syncthreads();
    float acc[8][8];
    #pragma unroll
    for (int i = 0; i < 8; ++i)
        #pragma unroll
        for (int j = 0; j < 8; ++j) acc[i][j] = 0.f;
    #pragma unroll 4
    for (int k = 0; k < 64; ++k) {
        float4 a0 = *(const float4*)&Qak[k][4*ty];
        float4 a1 = *(const float4*)&Qak[k][64 + 4*ty];
        float4 b0 = *(const float4*)&Qbk[k][4*tx];
        float4 b1 = *(const float4*)&Qbk[k][64 + 4*tx];
        float a[8] = {a0.x,a0.y,a0.z,a0.w,a1.x,a1.y,a1.z,a1.w};
        float b[8] = {b0.x,b0.y,b0.z,b0.w,b1.x,b1.y,b1.z,b1.w};
        #pragma unroll
        for (int i = 0; i < 8; ++i)
            #pragma unroll
            for (int j = 0; j < 8; ++j)
                acc[i][j] = fmaf(a[i], b[j], acc[i][j]);
    }
    u16* Kb = Kmat + (size_t)bh * 65536;
    #pragma unroll
    for (int rp = 0; rp < 2; ++rp)
        #pragma unroll
        for (int i = 0; i < 4; ++i) {
            const int gr = tr + rp*64 + 4*ty + i;
            #pragma unroll
            for (int cp = 0; cp < 2; ++cp) {
                const int gc0 = tc + cp*64 + 4*tx;
                float km[4];
                #pragma unroll
                for (int j = 0; j < 4; ++j) {
                    const float s = acc[rp*4+i][cp*4+j];
                    km[j] = (gr == gc0 + j) ? 0.f : __expf(fmaf(10.f, s, -10.f));
                }
                *(uint2*)&Kb[(size_t)gr * 256 + gc0] =
                    make_uint2(pack2bf(km[0], km[1]), pack2bf(km[2], km[3]));
            }
        }
}

// =======================================================================
// K3: exp-domain Sinkhorn, one block per (b,h). K is symmetric, so both
// updates are y[c] = sum_n K[n][c] * x[n] (coalesced row-major reads).
// 20 matvecs, then fused Tmax = max(u K v) reduction.
// =======================================================================
__global__ __launch_bounds__(256)
void sinkhorn_kernel(const u16* __restrict__ Kmat, float* __restrict__ ubuf,
                     float* __restrict__ vbuf, float* __restrict__ tmaxbuf)
{
    const int bh = blockIdx.x;
    const u16* Km = Kmat + (size_t)bh * 65536;
    __shared__ float xv[256];
    __shared__ float usave[256];
    __shared__ float part[8][256];
    const int tid = threadIdx.x;
    const int t = tid & 31;      // owns cols 8t..8t+7
    const int g = tid >> 5;      // owns rows g*32..g*32+31
    xv[tid] = 1.0f;
    __syncthreads();
    for (int it = 0; it < 20; ++it) {
        float y[8] = {0,0,0,0,0,0,0,0};
        #pragma unroll 4
        for (int nn = 0; nn < 32; ++nn) {
            const int n = g * 32 + nn;
            const uint4 raw = *(const uint4*)&Km[(size_t)n * 256 + t * 8];
            const float xn = xv[n];
            y[0] = fmaf(bf2f((u16)(raw.x & 0xffffu)), xn, y[0]);
            y[1] = fmaf(bf2f((u16)(raw.x >> 16)),     xn, y[1]);
            y[2] = fmaf(bf2f((u16)(raw.y & 0xffffu)), xn, y[2]);
            y[3] = fmaf(bf2f((u16)(raw.y >> 16)),     xn, y[3]);
            y[4] = fmaf(bf2f((u16)(raw.z & 0xffffu)), xn, y[4]);
            y[5] = fmaf(bf2f((u16)(raw.z >> 16)),     xn, y[5]);
            y[6] = fmaf(bf2f((u16)(raw.w & 0xffffu)), xn, y[6]);
            y[7] = fmaf(bf2f((u16)(raw.w >> 16)),     xn, y[7]);
        }
        *(float4*)&part[g][t*8]     = make_float4(y[0], y[1], y[2], y[3]);
        *(float4*)&part[g][t*8 + 4] = make_float4(y[4], y[5], y[6], y[7]);
        __syncthreads();
        float s = 0.f;
        #pragma unroll
        for (int gg = 0; gg < 8; ++gg) s += part[gg][tid];
        const float xn = 0.00390625f / s;       // (1/256)/s
        if (it == 18) usave[tid] = xn;          // last u-update
        xv[tid] = xn;
        __syncthreads();
    }
    // Tmax = max over (n,m) of u[n]*K[n][m]*v[m]
    float vx[8];
    #pragma unroll
    for (int q = 0; q < 8; ++q) vx[q] = xv[t*8 + q];
    float mx = 0.f;
    for (int nn = 0; nn < 32; ++nn) {
        const int n = g * 32 + nn;
        const uint4 raw = *(const uint4*)&Km[(size_t)n * 256 + t * 8];
        const float un = usave[n];
        mx = fmaxf(mx, un * bf2f((u16)(raw.x & 0xffffu)) * vx[0]);
        mx = fmaxf(mx, un * bf2f((u16)(raw.x >> 16))     * vx[1]);
        mx = fmaxf(mx, un * bf2f((u16)(raw.y & 0xffffu)) * vx[2]);
        mx = fmaxf(mx, un * bf2f((u16)(raw.y >> 16))     * vx[3]);
        mx = fmaxf(mx, un * bf2f((u16)(raw.z & 0xffffu)) * vx[4]);
        mx = fmaxf(mx, un * bf2f((u16)(raw.z >> 16))     * vx[5]);
        mx = fmaxf(mx, un * bf2f((u16)(raw.w & 0xffffu)) * vx[6]);
        mx = fmaxf(mx, un * bf2f((u16)(raw.w >> 16))     * vx[7]);
    }
    part[0][tid] = mx;
    __syncthreads();
    for (int sft = 128; sft > 0; sft >>= 1) {
        if (tid < sft) part[0][tid] = fmaxf(part[0][tid], part[0][tid + sft]);
        __syncthreads();
    }
    ubuf[bh * 256 + tid] = usave[tid];
    vbuf[bh * 256 + tid] = xv[tid];
    if (tid == 0) tmaxbuf[bh] = part[0][0];
}

// =======================================================================
// K4: per (b,h): z = u*K*v/Tmax (diag=1), p = exp(z*0.125), PV with
// late division by row-sum. attn staged transposed+swizzled bf16 in LDS.
// LDS = 32KB attnT + 32KB V = 64KB exact.
// =======================================================================
__global__ __launch_bounds__(256)
void softpv_kernel(const u16* __restrict__ Kmat, const float* __restrict__ vfeat,
                   const float* __restrict__ ubuf, const float* __restrict__ vbuf,
                   const float* __restrict__ tmaxbuf, float* __restrict__ ctx)
{
    __shared__ u16 attnT[64][256];   // [m_local][n ^ swz]
    __shared__ u16 Vs[256][64];      // [m][d] bf16
    const int bh = blockIdx.x;
    const int b_ = bh / 12, h_ = bh % 12;
    const u16* Km = Kmat + (size_t)bh * 65536;
    const float* ub = ubuf + bh * 256;
    const float* vb = vbuf + bh * 256;
    const int tid  = threadIdx.x;
    const int lane = tid & 63, w = tid >> 6;
    const int tx = tid & 15,  ty = tid >> 4;
    const float itmax = 1.0f / tmaxbuf[bh];
    {
        const float* Vg = vfeat + (size_t)bh * 16384;
        const int mq = tid >> 4, qq = tid & 15;
        #pragma unroll
        for (int pass = 0; pass < 16; ++pass) {
            const int m = pass * 16 + mq;
            float4 vv = *(const float4*)&Vg[(size_t)m * 64 + qq * 4];
            *(uint2*)&Vs[m][qq * 4] = make_uint2(pack2bf(vv.x, vv.y), pack2bf(vv.z, vv.w));
        }
    }
    float acc[4][4][4] = {};
    float psum_reg = 0.f;
    const int swz = (lane & 15) << 2;
    __syncthreads();
    for (int mc = 0; mc < 4; ++mc) {
        const int m = mc * 64 + lane;
        const float vm = vb[m];
        // ---- P1: probabilities for rows w*64..w*64+63, cols mc*64..+63
        for (int rr = 0; rr < 64; ++rr) {
            const int n = w * 64 + rr;
            const float un = ub[n];
            const float kmv = bf2f(Km[(size_t)n * 256 + m]);
            float z = un * kmv * vm * itmax;
            if (m == n) z = 1.0f;
            const u16 pb = f2bf(__expf(z * 0.125f));
            attnT[lane][n ^ swz] = pb;
            float r = bf2f(pb);
            #pragma unroll
            for (int off = 1; off < 64; off <<= 1) r += __shfl_xor(r, off);
            if (lane == rr) psum_reg += r;
        }
        __syncthreads();
        // ---- P2: acc += attn_chunk^T-read x V_chunk
        #pragma unroll 2
        for (int k = 0; k < 64; ++k) {
            const uint2 vp = *(const uint2*)&Vs[mc * 64 + k][4 * tx];
            float bvv[4];
            bvv[0] = bf2f((u16)(vp.x & 0xffffu)); bvv[1] = bf2f((u16)(vp.x >> 16));
            bvv[2] = bf2f((u16)(vp.y & 0xffffu)); bvv[3] = bf2f((u16)(vp.y >> 16));
            const int ksw = (k & 15) << 2;
            #pragma unroll
            for (int rp = 0; rp < 4; ++rp) {
                const int coff = (rp * 64 + 4 * ty) ^ ksw;
                const uint2 ap = *(const uint2*)&attnT[k][coff];
                float av[4];
                av[0] = bf2f((u16)(ap.x & 0xffffu)); av[1] = bf2f((u16)(ap.x >> 16));
                av[2] = bf2f((u16)(ap.y & 0xffffu)); av[3] = bf2f((u16)(ap.y >> 16));
                #pragma unroll
                for (int i = 0; i < 4; ++i)
                    #pragma unroll
                    for (int j = 0; j < 4; ++j)
                        acc[rp][i][j] = fmaf(av[i], bvv[j], acc[rp][i][j]);
            }
        }
        __syncthreads();
    }
    // publish row denominators (reuse attnT storage as float[256])
    float* psf = (float*)&attnT[0][0];
    psf[w * 64 + lane] = psum_reg;
    __syncthreads();
    #pragma unroll
    for (int rp = 0; rp < 4; ++rp)
        #pragma unroll
        for (int i = 0; i < 4; ++i) {
            const int n = rp * 64 + 4 * ty + i;
            const float inv = 1.0f / psf[n];
            float4 o4 = make_float4(acc[rp][i][0] * inv, acc[rp][i][1] * inv,
                                    acc[rp][i][2] * inv, acc[rp][i][3] * inv);
            *(float4*)&ctx[((size_t)b_ * 256 + n) * 768 + h_ * 64 + 4 * tx] = o4;
        }
}

// =======================================================================
// K5: out = ctx @ w_proj^T + b_proj.  ctx: [16384, 768] fp32.
// =======================================================================
__global__ __launch_bounds__(256)
void gemm_proj(const float* __restrict__ A, const float* __restrict__ W,
               const float* __restrict__ bias, float* __restrict__ out)
{
    __shared__ float Ask[32][128];
    __shared__ float Bsk[32][128];
    const int m0  = blockIdx.x * 128;
    const int ow0 = blockIdx.y * 128;
    const int tid = threadIdx.x;
    const int tx = tid & 15, ty = tid >> 4;
    const int lr = tid >> 1;
    const int lkb = (tid & 1) * 16;
    float acc[8][8];
    #pragma unroll
    for (int i = 0; i < 8; ++i)
        #pragma unroll
        for (int j = 0; j < 8; ++j) acc[i][j] = 0.f;

    for (int k0 = 0; k0 < 768; k0 += 32) {
        #pragma unroll
        for (int q = 0; q < 4; ++q) {
            const int kk = lkb + q * 4;
            float4 av = *(const float4*)&A[(size_t)(m0 + lr) * 768 + k0 + kk];
            Ask[kk+0][lr] = av.x; Ask[kk+1][lr] = av.y;
            Ask[kk+2][lr] = av.z; Ask[kk+3][lr] = av.w;
            float4 wv = *(const float4*)&W[(size_t)(ow0 + lr) * 768 + k0 + kk];
            Bsk[kk+0][lr] = wv.x; Bsk[kk+1][lr] = wv.y;
            Bsk[kk+2][lr] = wv.z; Bsk[kk+3][lr] = wv.w;
        }
        __syncthreads();
        #pragma unroll 4
        for (int kk = 0; kk < 32; ++kk) {
            float4 a0 = *(const float4*)&Ask[kk][4*ty];
            float4 a1 = *(const float4*)&Ask[kk][64 + 4*ty];
            float4 b0 = *(const float4*)&Bsk[kk][4*tx];
            float4 b1 = *(const float4*)&Bsk[kk][64 + 4*tx];
            float a[8] = {a0.x,a0.y,a0.z,a0.w,a1.x,a1.y,a1.z,a1.w};
            float b[8] = {b0.x,b0.y,b0.z,b0.w,b1.x,b1.y,b1.z,b1.w};
            #pragma unroll
            for (int i = 0; i < 8; ++i)
                #pragma unroll
                for (int j = 0; j < 8; ++j)
                    acc[i][j] = fmaf(a[i], b[j], acc[i][j]);
        }
        __syncthreads();
    }
    #pragma unroll
    for (int rp = 0; rp < 2; ++rp)
        #pragma unroll
        for (int i = 0; i < 4; ++i) {
            const int m = m0 + rp*64 + 4*ty + i;
            #pragma unroll
            for (int cp = 0; cp < 2; ++cp) {
                const int oc = ow0 + cp*64 + 4*tx;
                float4 bv = *(const float4*)&bias[oc];
                float4 o4 = make_float4(acc[rp*4+i][cp*4+0] + bv.x,
                                        acc[rp*4+i][cp*4+1] + bv.y,
                                        acc[rp*4+i][cp*4+2] + bv.z,
                                        acc[rp*4+i][cp*4+3] + bv.w);
                *(float4*)&out[(size_t)m * 768 + oc] = o4;
            }
        }
}

// =======================================================================
extern "C" void kernel_launch(void* const* d_in, const int* in_sizes, int n_in,
                              void* d_out, int out_size, void* d_ws, size_t ws_size,
                              hipStream_t stream)
{
    (void)in_sizes; (void)n_in; (void)out_size; (void)ws_size;
    const float* x      = (const float*)d_in[0];
    const float* w_qkv  = (const float*)d_in[1];
    const float* w_proj = (const float*)d_in[2];
    const float* b_proj = (const float*)d_in[3];
    float* out = (float*)d_out;

    char* w = (char*)d_ws;
    // workspace layout (bytes):
    float* qbuf = (float*)(w);                     // 50,331,648  q [768][256][64]
    float* vbuf = (float*)(w + 50331648);          // 50,331,648  v [768][256][64]
    float* ctxb = (float*)(w + 100663296);         // 50,331,648  ctx [64][256][768]
    float* ub   = (float*)(w + 150994944);         //    786,432  u [768][256]
    float* vb   = (float*)(w + 151781376);         //    786,432  v [768][256]
    float* tmx  = (float*)(w + 152567808);         //      3,072  tmax [768]
    u16*   Km   = (u16*)  (w + 152570880);         // 100,663,296 K bf16 [768][256][256]
    // total ~253.3 MB

    gemm_qkv        <<<dim3(128, 12), 256, 0, stream>>>(x, w_qkv, qbuf, vbuf);
    normalize_kernel<<<dim3(49152),   256, 0, stream>>>(qbuf);
    cost_kernel     <<<dim3(4, 768),  256, 0, stream>>>(qbuf, Km);
    sinkhorn_kernel <<<dim3(768),     256, 0, stream>>>(Km, ub, vb, tmx);
    softpv_kernel   <<<dim3(768),     256, 0, stream>>>(Km, vbuf, ub, vb, tmx, ctxb);
    gemm_proj       <<<dim3(128, 6),  256, 0, stream>>>(ctxb, w_proj, b_proj, out);
}

// Round 2
// 728.828 us; speedup vs baseline: 1.7466x; 1.7466x over previous
//
#include <hip/hip_runtime.h>

typedef unsigned short u16;
typedef unsigned int   u32;
typedef __attribute__((ext_vector_type(8))) short bf16x8;
typedef __attribute__((ext_vector_type(4))) float f32x4;

// ---------- bf16 helpers (manual, RNE) ----------
__device__ __forceinline__ u16 f2bf(float f) {
    u32 u = __float_as_uint(f);
    u += 0x7fffu + ((u >> 16) & 1u);
    return (u16)(u >> 16);
}
__device__ __forceinline__ float bf2f(u16 s) {
    return __uint_as_float(((u32)s) << 16);
}
__device__ __forceinline__ u32 pack2bf(float f0, float f1) {
    return (u32)f2bf(f0) | ((u32)f2bf(f1) << 16);
}

__device__ __forceinline__ void gload_lds16(const void* g, void* l) {
    __builtin_amdgcn_global_load_lds(
        (const __attribute__((address_space(1))) u32*)g,
        (__attribute__((address_space(3))) u32*)l, 16, 0, 0);
}

// =======================================================================
// fp32 -> bf16 converters
// =======================================================================
__global__ __launch_bounds__(256)
void conv_bf16(const float* __restrict__ src, u16* __restrict__ dst, int n8)
{
    const int i = blockIdx.x * 256 + threadIdx.x;   // 8 elements per thread
    if (i < n8) {
        const float4 a = ((const float4*)src)[2*i];
        const float4 b = ((const float4*)src)[2*i + 1];
        ((uint4*)dst)[i] = make_uint4(pack2bf(a.x,a.y), pack2bf(a.z,a.w),
                                      pack2bf(b.x,b.y), pack2bf(b.z,b.w));
    }
}

// w_qkv [2304][768]: keep q rows 0..767 and v rows 1536..2303 -> wqv [1536][768]
__global__ __launch_bounds__(256)
void conv_wqv(const float* __restrict__ w, u16* __restrict__ dst)
{
    const int i = blockIdx.x * 256 + threadIdx.x;   // chunk of 8, 96 chunks/row
    const int row = i / 96;
    const int cc  = (i - row * 96) * 8;
    const int srow = row + (row >= 768 ? 768 : 0);
    const float4 a = *(const float4*)&w[(size_t)srow*768 + cc];
    const float4 b = *(const float4*)&w[(size_t)srow*768 + cc + 4];
    *(uint4*)&dst[(size_t)row*768 + cc] =
        make_uint4(pack2bf(a.x,a.y), pack2bf(a.z,a.w), pack2bf(b.x,b.y), pack2bf(b.z,b.w));
}

// =======================================================================
// Shared MFMA GEMM core: C[128x128] tile, K=768, bf16 A[.,768] x B[.,768]^T.
// BK=64, 4 waves (2x2), 16x16x32 MFMA, global_load_lds + XOR-swizzled LDS.
// LDS layout: row-major [128 rows][128 bytes]; position (r, c') holds
// A[r][c' ^ 16*(r&7)] (bytes). Staged via inverse-swizzled global source,
// read back with the same XOR. Staging: issue i, wave w, lane l -> LDS byte
// i*4096 + w*1024 + l*16 => r = i*32 + w*8 + (l>>3) (so r&7 == l>>3),
// bytecol (l&7)*16; global col bytes = 16*((l&7) ^ (l>>3)).
// =======================================================================
__device__ __forceinline__ void mfma_gemm_core(
    const char* __restrict__ Arow0,   // &A[m0][0] as bytes (row stride 1536)
    const char* __restrict__ Brow0,   // &B[n0][0] as bytes
    u16* As, u16* Bs, const int tid, f32x4 acc[4][4])
{
    const int l  = tid & 63, w = tid >> 6;
    const int wr = w >> 1,  wc = w & 1;
    char* Asb = (char*)As;
    char* Bsb = (char*)Bs;
    const int co = 16 * ((l & 7) ^ (l >> 3));       // swizzled global byte col
    const size_t rstep = (size_t)(l >> 3) * 1536;
    const int rsw = (l & 7) << 4;                   // read-side XOR

    for (int k0 = 0; k0 < 1536; k0 += 128) {        // 12 K-steps of 64 bf16
        #pragma unroll
        for (int i = 0; i < 4; ++i) {
            const int rb = i*32 + w*8;
            gload_lds16(Arow0 + (size_t)rb*1536 + rstep + k0 + co, Asb + i*4096 + w*1024);
            gload_lds16(Brow0 + (size_t)rb*1536 + rstep + k0 + co, Bsb + i*4096 + w*1024);
        }
        __syncthreads();
        bf16x8 af[2][4], bfr[2][4];
        #pragma unroll
        for (int kk = 0; kk < 2; ++kk) {
            const int coff = (kk*64 + ((l >> 4) << 4)) ^ rsw;
            #pragma unroll
            for (int mi = 0; mi < 4; ++mi) {
                const int rowA = wr*64 + mi*16 + (l & 15);
                af[kk][mi]  = *(const bf16x8*)(Asb + rowA*128 + coff);
                const int rowB = wc*64 + mi*16 + (l & 15);
                bfr[kk][mi] = *(const bf16x8*)(Bsb + rowB*128 + coff);
            }
        }
        #pragma unroll
        for (int mi = 0; mi < 4; ++mi)
            #pragma unroll
            for (int nj = 0; nj < 4; ++nj) {
                acc[mi][nj] = __builtin_amdgcn_mfma_f32_16x16x32_bf16(
                                  af[0][mi], bfr[0][nj], acc[mi][nj], 0, 0, 0);
                acc[mi][nj] = __builtin_amdgcn_mfma_f32_16x16x32_bf16(
                                  af[1][mi], bfr[1][nj], acc[mi][nj], 0, 0, 0);
            }
        __syncthreads();
    }
}

// =======================================================================
// K0: q/v projection. xbf [16384][768] bf16, wqv [1536][768] bf16.
// bj<6 -> q cols (fp32 out, [bh][n][64]); bj>=6 -> v cols (bf16 out).
// =======================================================================
__global__ __launch_bounds__(256)
void gemm_qkv_mfma(const u16* __restrict__ xbf, const u16* __restrict__ wqv,
                   float* __restrict__ qbuf, u16* __restrict__ vbf)
{
    __shared__ u16 As[128*64];
    __shared__ u16 Bs[128*64];
    const int m0 = blockIdx.x * 128;
    const int bj = blockIdx.y;
    const int tid = threadIdx.x;
    f32x4 acc[4][4];
    #pragma unroll
    for (int i = 0; i < 4; ++i)
        #pragma unroll
        for (int j = 0; j < 4; ++j) acc[i][j] = (f32x4){0.f,0.f,0.f,0.f};

    mfma_gemm_core((const char*)xbf + (size_t)m0*1536,
                   (const char*)wqv + (size_t)bj*128*1536,
                   As, Bs, tid, acc);

    const int l = tid & 63, w = tid >> 6;
    const int wr = w >> 1, wc = w & 1;
    const int colb = (bj % 6)*128 + wc*64;
    const int rbase = m0 + wr*64 + ((l >> 4) << 2);
    if (bj < 6) {
        #pragma unroll
        for (int mi = 0; mi < 4; ++mi)
            #pragma unroll
            for (int nj = 0; nj < 4; ++nj) {
                const int col = colb + nj*16 + (l & 15);
                const int h = col >> 6, d = col & 63;
                #pragma unroll
                for (int rr = 0; rr < 4; ++rr) {
                    const int m = rbase + mi*16 + rr;
                    const int b_ = m >> 8, n_ = m & 255;
                    qbuf[((((size_t)b_*12 + h) << 8) + n_)*64 + d] = acc[mi][nj][rr];
                }
            }
    } else {
        #pragma unroll
        for (int mi = 0; mi < 4; ++mi)
            #pragma unroll
            for (int nj = 0; nj < 4; ++nj) {
                const int col = colb + nj*16 + (l & 15);
                const int h = col >> 6, d = col & 63;
                #pragma unroll
                for (int rr = 0; rr < 4; ++rr) {
                    const int m = rbase + mi*16 + rr;
                    const int b_ = m >> 8, n_ = m & 255;
                    vbf[((((size_t)b_*12 + h) << 8) + n_)*64 + d] = f2bf(acc[mi][nj][rr]);
                }
            }
    }
}

// =======================================================================
// K5: out = ctx @ w_proj^T + b_proj. ctxb [16384][768] bf16, wpb [768][768] bf16.
// =======================================================================
__global__ __launch_bounds__(256)
void gemm_proj_mfma(const u16* __restrict__ ctxb, const u16* __restrict__ wpb,
                    const float* __restrict__ bias, float* __restrict__ out)
{
    __shared__ u16 As[128*64];
    __shared__ u16 Bs[128*64];
    const int m0 = blockIdx.x * 128;
    const int n0 = blockIdx.y * 128;
    const int tid = threadIdx.x;
    f32x4 acc[4][4];
    #pragma unroll
    for (int i = 0; i < 4; ++i)
        #pragma unroll
        for (int j = 0; j < 4; ++j) acc[i][j] = (f32x4){0.f,0.f,0.f,0.f};

    mfma_gemm_core((const char*)ctxb + (size_t)m0*1536,
                   (const char*)wpb + (size_t)n0*1536,
                   As, Bs, tid, acc);

    const int l = tid & 63, w = tid >> 6;
    const int wr = w >> 1, wc = w & 1;
    const int rbase = m0 + wr*64 + ((l >> 4) << 2);
    #pragma unroll
    for (int mi = 0; mi < 4; ++mi)
        #pragma unroll
        for (int nj = 0; nj < 4; ++nj) {
            const int col = n0 + wc*64 + nj*16 + (l & 15);
            const float bv = bias[col];
            #pragma unroll
            for (int rr = 0; rr < 4; ++rr) {
                const int m = rbase + mi*16 + rr;
                out[(size_t)m*768 + col] = acc[mi][nj][rr] + bv;
            }
        }
}

// =======================================================================
// K1: normalize q rows in place: q /= (||q|| + 1e-8). One wave per row.
// =======================================================================
__global__ __launch_bounds__(256)
void normalize_kernel(float* __restrict__ q)
{
    const int row = blockIdx.x * 4 + (threadIdx.x >> 6);
    const int d   = threadIdx.x & 63;
    const size_t idx = (size_t)row * 64 + d;
    const float val = q[idx];
    float s = val * val;
    #pragma unroll
    for (int off = 32; off > 0; off >>= 1) s += __shfl_xor(s, off);
    q[idx] = val / (sqrtf(s) + 1e-8f);
}

// =======================================================================
// K2: K[n][m] = exp(10*cos(n,m) - 10) off-diag, 0 on diag. bf16 out.
// =======================================================================
__global__ __launch_bounds__(256)
void cost_kernel(const float* __restrict__ qn, u16* __restrict__ Kmat)
{
    __shared__ float Qak[64][128];
    __shared__ float Qbk[64][128];
    const int bh = blockIdx.y;
    const int tr = (blockIdx.x >> 1) * 128;
    const int tc = (blockIdx.x & 1) * 128;
    const float* qb = qn + (size_t)bh * (256 * 64);
    const int tid = threadIdx.x;
    const int tx = tid & 15, ty = tid >> 4;
    {
        const int r  = tid >> 1;            // 0..127
        const int kb = (tid & 1) * 32;
        #pragma unroll
        for (int qq = 0; qq < 8; ++qq) {
            const int k = kb + qq * 4;
            float4 a = *(const float4*)&qb[(size_t)(tr + r) * 64 + k];
            Qak[k+0][r] = a.x; Qak[k+1][r] = a.y; Qak[k+2][r] = a.z; Qak[k+3][r] = a.w;
            float4 b = *(const float4*)&qb[(size_t)(tc + r) * 64 + k];
            Qbk[k+0][r] = b.x; Qbk[k+1][r] = b.y; Qbk[k+2][r] = b.z; Qbk[k+3][r] = b.w;
        }
    }
    __syncthreads();
    float acc[8][8];
    #pragma unroll
    for (int i = 0; i < 8; ++i)
        #pragma unroll
        for (int j = 0; j < 8; ++j) acc[i][j] = 0.f;
    #pragma unroll 4
    for (int k = 0; k < 64; ++k) {
        float4 a0 = *(const float4*)&Qak[k][4*ty];
        float4 a1 = *(const float4*)&Qak[k][64 + 4*ty];
        float4 b0 = *(const float4*)&Qbk[k][4*tx];
        float4 b1 = *(const float4*)&Qbk[k][64 + 4*tx];
        float a[8] = {a0.x,a0.y,a0.z,a0.w,a1.x,a1.y,a1.z,a1.w};
        float b[8] = {b0.x,b0.y,b0.z,b0.w,b1.x,b1.y,b1.z,b1.w};
        #pragma unroll
        for (int i = 0; i < 8; ++i)
            #pragma unroll
            for (int j = 0; j < 8; ++j)
                acc[i][j] = fmaf(a[i], b[j], acc[i][j]);
    }
    u16* Kb = Kmat + (size_t)bh * 65536;
    #pragma unroll
    for (int rp = 0; rp < 2; ++rp)
        #pragma unroll
        for (int i = 0; i < 4; ++i) {
            const int gr = tr + rp*64 + 4*ty + i;
            #pragma unroll
            for (int cp = 0; cp < 2; ++cp) {
                const int gc0 = tc + cp*64 + 4*tx;
                float km[4];
                #pragma unroll
                for (int j = 0; j < 4; ++j) {
                    const float s = acc[rp*4+i][cp*4+j];
                    km[j] = (gr == gc0 + j) ? 0.f : __expf(fmaf(10.f, s, -10.f));
                }
                *(uint2*)&Kb[(size_t)gr * 256 + gc0] =
                    make_uint2(pack2bf(km[0], km[1]), pack2bf(km[2], km[3]));
            }
        }
}

// =======================================================================
// K3: exp-domain Sinkhorn, one block per (b,h). K symmetric -> both updates
// are column-sums with coalesced row-major reads. 20 matvecs + Tmax.
// =======================================================================
__global__ __launch_bounds__(256)
void sinkhorn_kernel(const u16* __restrict__ Kmat, float* __restrict__ ubuf,
                     float* __restrict__ vbuf, float* __restrict__ tmaxbuf)
{
    const int bh = blockIdx.x;
    const u16* Km = Kmat + (size_t)bh * 65536;
    __shared__ float xv[256];
    __shared__ float usave[256];
    __shared__ float part[8][256];
    const int tid = threadIdx.x;
    const int t = tid & 31;      // owns cols 8t..8t+7
    const int g = tid >> 5;      // owns rows g*32..g*32+31
    xv[tid] = 1.0f;
    __syncthreads();
    for (int it = 0; it < 20; ++it) {
        float y[8] = {0,0,0,0,0,0,0,0};
        #pragma unroll 4
        for (int nn = 0; nn < 32; ++nn) {
            const int n = g * 32 + nn;
            const uint4 raw = *(const uint4*)&Km[(size_t)n * 256 + t * 8];
            const float xn = xv[n];
            y[0] = fmaf(bf2f((u16)(raw.x & 0xffffu)), xn, y[0]);
            y[1] = fmaf(bf2f((u16)(raw.x >> 16)),     xn, y[1]);
            y[2] = fmaf(bf2f((u16)(raw.y & 0xffffu)), xn, y[2]);
            y[3] = fmaf(bf2f((u16)(raw.y >> 16)),     xn, y[3]);
            y[4] = fmaf(bf2f((u16)(raw.z & 0xffffu)), xn, y[4]);
            y[5] = fmaf(bf2f((u16)(raw.z >> 16)),     xn, y[5]);
            y[6] = fmaf(bf2f((u16)(raw.w & 0xffffu)), xn, y[6]);
            y[7] = fmaf(bf2f((u16)(raw.w >> 16)),     xn, y[7]);
        }
        *(float4*)&part[g][t*8]     = make_float4(y[0], y[1], y[2], y[3]);
        *(float4*)&part[g][t*8 + 4] = make_float4(y[4], y[5], y[6], y[7]);
        __syncthreads();
        float s = 0.f;
        #pragma unroll
        for (int gg = 0; gg < 8; ++gg) s += part[gg][tid];
        const float xn = 0.00390625f / s;       // (1/256)/s
        if (it == 18) usave[tid] = xn;          // last u-update
        xv[tid] = xn;
        __syncthreads();
    }
    float vx[8];
    #pragma unroll
    for (int q = 0; q < 8; ++q) vx[q] = xv[t*8 + q];
    float mx = 0.f;
    for (int nn = 0; nn < 32; ++nn) {
        const int n = g * 32 + nn;
        const uint4 raw = *(const uint4*)&Km[(size_t)n * 256 + t * 8];
        const float un = usave[n];
        mx = fmaxf(mx, un * bf2f((u16)(raw.x & 0xffffu)) * vx[0]);
        mx = fmaxf(mx, un * bf2f((u16)(raw.x >> 16))     * vx[1]);
        mx = fmaxf(mx, un * bf2f((u16)(raw.y & 0xffffu)) * vx[2]);
        mx = fmaxf(mx, un * bf2f((u16)(raw.y >> 16))     * vx[3]);
        mx = fmaxf(mx, un * bf2f((u16)(raw.z & 0xffffu)) * vx[4]);
        mx = fmaxf(mx, un * bf2f((u16)(raw.z >> 16))     * vx[5]);
        mx = fmaxf(mx, un * bf2f((u16)(raw.w & 0xffffu)) * vx[6]);
        mx = fmaxf(mx, un * bf2f((u16)(raw.w >> 16))     * vx[7]);
    }
    part[0][tid] = mx;
    __syncthreads();
    for (int sft = 128; sft > 0; sft >>= 1) {
        if (tid < sft) part[0][tid] = fmaxf(part[0][tid], part[0][tid + sft]);
        __syncthreads();
    }
    ubuf[bh * 256 + tid] = usave[tid];
    vbuf[bh * 256 + tid] = xv[tid];
    if (tid == 0) tmaxbuf[bh] = part[0][0];
}

// =======================================================================
// K4: per (b,h): z = u*K*v/Tmax (diag=1), p = exp(z*0.125), PV, late
// row-sum division. attnT bf16 swizzled in LDS; V now bf16 direct copy.
// ctx written as bf16 [b][n][768] for the proj MFMA GEMM.
// =======================================================================
__global__ __launch_bounds__(256)
void softpv_kernel(const u16* __restrict__ Kmat, const u16* __restrict__ vbf,
                   const float* __restrict__ ubuf, const float* __restrict__ vbuf,
                   const float* __restrict__ tmaxbuf, u16* __restrict__ ctxc)
{
    __shared__ u16 attnT[64][256];   // [m_local][n ^ swz]
    __shared__ u16 Vs[256][64];      // [m][d] bf16
    const int bh = blockIdx.x;
    const int b_ = bh / 12, h_ = bh % 12;
    const u16* Km = Kmat + (size_t)bh * 65536;
    const float* ub = ubuf + bh * 256;
    const float* vb = vbuf + bh * 256;
    const int tid  = threadIdx.x;
    const int lane = tid & 63, w = tid >> 6;
    const int tx = tid & 15,  ty = tid >> 4;
    const float itmax = 1.0f / tmaxbuf[bh];
    {
        const uint4* Vg4 = (const uint4*)(vbf + (size_t)bh * 16384);
        uint4* Vs4 = (uint4*)&Vs[0][0];
        #pragma unroll
        for (int p = 0; p < 8; ++p) Vs4[p*256 + tid] = Vg4[p*256 + tid];
    }
    float acc[4][4][4] = {};
    float psum_reg = 0.f;
    const int swz = (lane & 15) << 2;
    __syncthreads();
    for (int mc = 0; mc < 4; ++mc) {
        const int m = mc * 64 + lane;
        const float vm = vb[m];
        for (int rr = 0; rr < 64; ++rr) {
            const int n = w * 64 + rr;
            const float un = ub[n];
            const float kmv = bf2f(Km[(size_t)n * 256 + m]);
            float z = un * kmv * vm * itmax;
            if (m == n) z = 1.0f;
            const u16 pb = f2bf(__expf(z * 0.125f));
            attnT[lane][n ^ swz] = pb;
            float r = bf2f(pb);
            #pragma unroll
            for (int off = 1; off < 64; off <<= 1) r += __shfl_xor(r, off);
            if (lane == rr) psum_reg += r;
        }
        __syncthreads();
        #pragma unroll 2
        for (int k = 0; k < 64; ++k) {
            const uint2 vp = *(const uint2*)&Vs[mc * 64 + k][4 * tx];
            float bvv[4];
            bvv[0] = bf2f((u16)(vp.x & 0xffffu)); bvv[1] = bf2f((u16)(vp.x >> 16));
            bvv[2] = bf2f((u16)(vp.y & 0xffffu)); bvv[3] = bf2f((u16)(vp.y >> 16));
            const int ksw = (k & 15) << 2;
            #pragma unroll
            for (int rp = 0; rp < 4; ++rp) {
                const int coff = (rp * 64 + 4 * ty) ^ ksw;
                const uint2 ap = *(const uint2*)&attnT[k][coff];
                float av[4];
                av[0] = bf2f((u16)(ap.x & 0xffffu)); av[1] = bf2f((u16)(ap.x >> 16));
                av[2] = bf2f((u16)(ap.y & 0xffffu)); av[3] = bf2f((u16)(ap.y >> 16));
                #pragma unroll
                for (int i = 0; i < 4; ++i)
                    #pragma unroll
                    for (int j = 0; j < 4; ++j)
                        acc[rp][i][j] = fmaf(av[i], bvv[j], acc[rp][i][j]);
            }
        }
        __syncthreads();
    }
    float* psf = (float*)&attnT[0][0];
    psf[w * 64 + lane] = psum_reg;
    __syncthreads();
    #pragma unroll
    for (int rp = 0; rp < 4; ++rp)
        #pragma unroll
        for (int i = 0; i < 4; ++i) {
            const int n = rp * 64 + 4 * ty + i;
            const float inv = 1.0f / psf[n];
            *(uint2*)&ctxc[((size_t)b_ * 256 + n) * 768 + h_ * 64 + 4 * tx] =
                make_uint2(pack2bf(acc[rp][i][0] * inv, acc[rp][i][1] * inv),
                           pack2bf(acc[rp][i][2] * inv, acc[rp][i][3] * inv));
        }
}

// =======================================================================
extern "C" void kernel_launch(void* const* d_in, const int* in_sizes, int n_in,
                              void* d_out, int out_size, void* d_ws, size_t ws_size,
                              hipStream_t stream)
{
    (void)in_sizes; (void)n_in; (void)out_size; (void)ws_size;
    const float* x      = (const float*)d_in[0];
    const float* w_qkv  = (const float*)d_in[1];
    const float* w_proj = (const float*)d_in[2];
    const float* b_proj = (const float*)d_in[3];
    float* out = (float*)d_out;

    char* w = (char*)d_ws;
    // workspace layout (bytes):
    u16*   xbf  = (u16*)  (w);                     //  25,165,824  x bf16 [16384][768]
    u16*   wqv  = (u16*)  (w + 25165824);          //   2,359,296  w q+v rows bf16 [1536][768]
    u16*   wpb  = (u16*)  (w + 27525120);          //   1,179,648  w_proj bf16 [768][768]
    float* qbuf = (float*)(w + 28704768);          //  50,331,648  q fp32 [768][256][64]
    u16*   vbf  = (u16*)  (w + 79036416);          //  25,165,824  v bf16 [768][256][64]
    u16*   ctxc = (u16*)  (w + 104202240);         //  25,165,824  ctx bf16 [64][256][768]
    float* ub   = (float*)(w + 129368064);         //     786,432  u [768][256]
    float* vb   = (float*)(w + 130154496);         //     786,432  v [768][256]
    float* tmx  = (float*)(w + 130940928);         //       3,072  tmax [768]
    u16*   Km   = (u16*)  (w + 130944000);         // 100,663,296  K bf16 [768][256][256]
    // total ~231.6 MB

    conv_bf16       <<<dim3(6144),    256, 0, stream>>>(x, xbf, 1572864);
    conv_wqv        <<<dim3(576),     256, 0, stream>>>(w_qkv, wqv);
    conv_bf16       <<<dim3(288),     256, 0, stream>>>(w_proj, wpb, 73728);
    gemm_qkv_mfma   <<<dim3(128, 12), 256, 0, stream>>>(xbf, wqv, qbuf, vbf);
    normalize_kernel<<<dim3(49152),   256, 0, stream>>>(qbuf);
    cost_kernel     <<<dim3(4, 768),  256, 0, stream>>>(qbuf, Km);
    sinkhorn_kernel <<<dim3(768),     256, 0, stream>>>(Km, ub, vb, tmx);
    softpv_kernel   <<<dim3(768),     256, 0, stream>>>(Km, vbf, ub, vb, tmx, ctxc);
    gemm_proj_mfma  <<<dim3(128, 6),  256, 0, stream>>>(ctxc, wpb, b_proj, out);
}

// Round 3
// 525.037 us; speedup vs baseline: 2.4246x; 1.3881x over previous
//
#include <hip/hip_runtime.h>

typedef unsigned short u16;
typedef unsigned int   u32;
typedef __attribute__((ext_vector_type(8))) short bf16x8;
typedef __attribute__((ext_vector_type(4))) float f32x4;

// ---------- bf16 helpers (manual, RNE) ----------
__device__ __forceinline__ u16 f2bf(float f) {
    u32 u = __float_as_uint(f);
    u += 0x7fffu + ((u >> 16) & 1u);
    return (u16)(u >> 16);
}
__device__ __forceinline__ float bf2f(u16 s) {
    return __uint_as_float(((u32)s) << 16);
}
__device__ __forceinline__ u32 pack2bf(float f0, float f1) {
    return (u32)f2bf(f0) | ((u32)f2bf(f1) << 16);
}

__device__ __forceinline__ void gload_lds16(const void* g, void* l) {
    __builtin_amdgcn_global_load_lds(
        (const __attribute__((address_space(1))) u32*)g,
        (__attribute__((address_space(3))) u32*)l, 16, 0, 0);
}

// =======================================================================
// fp32 -> bf16 converters
// =======================================================================
__global__ __launch_bounds__(256)
void conv_bf16(const float* __restrict__ src, u16* __restrict__ dst, int n8)
{
    const int i = blockIdx.x * 256 + threadIdx.x;   // 8 elements per thread
    if (i < n8) {
        const float4 a = ((const float4*)src)[2*i];
        const float4 b = ((const float4*)src)[2*i + 1];
        ((uint4*)dst)[i] = make_uint4(pack2bf(a.x,a.y), pack2bf(a.z,a.w),
                                      pack2bf(b.x,b.y), pack2bf(b.z,b.w));
    }
}

// w_qkv [2304][768]: keep q rows 0..767 and v rows 1536..2303 -> wqv [1536][768]
__global__ __launch_bounds__(256)
void conv_wqv(const float* __restrict__ w, u16* __restrict__ dst)
{
    const int i = blockIdx.x * 256 + threadIdx.x;   // chunk of 8, 96 chunks/row
    const int row = i / 96;
    const int cc  = (i - row * 96) * 8;
    const int srow = row + (row >= 768 ? 768 : 0);
    const float4 a = *(const float4*)&w[(size_t)srow*768 + cc];
    const float4 b = *(const float4*)&w[(size_t)srow*768 + cc + 4];
    *(uint4*)&dst[(size_t)row*768 + cc] =
        make_uint4(pack2bf(a.x,a.y), pack2bf(a.z,a.w), pack2bf(b.x,b.y), pack2bf(b.z,b.w));
}

// =======================================================================
// Shared MFMA GEMM core: C[128x128] tile, K=768, bf16 A[.,768] x B[.,768]^T.
// BK=64, 4 waves (2x2), 16x16x32 MFMA, global_load_lds + XOR-swizzled LDS.
// =======================================================================
__device__ __forceinline__ void mfma_gemm_core(
    const char* __restrict__ Arow0,   // &A[m0][0] as bytes (row stride 1536)
    const char* __restrict__ Brow0,   // &B[n0][0] as bytes
    u16* As, u16* Bs, const int tid, f32x4 acc[4][4])
{
    const int l  = tid & 63, w = tid >> 6;
    const int wr = w >> 1,  wc = w & 1;
    char* Asb = (char*)As;
    char* Bsb = (char*)Bs;
    const int co = 16 * ((l & 7) ^ (l >> 3));       // swizzled global byte col
    const size_t rstep = (size_t)(l >> 3) * 1536;
    const int rsw = (l & 7) << 4;                   // read-side XOR

    for (int k0 = 0; k0 < 1536; k0 += 128) {        // 12 K-steps of 64 bf16
        #pragma unroll
        for (int i = 0; i < 4; ++i) {
            const int rb = i*32 + w*8;
            gload_lds16(Arow0 + (size_t)rb*1536 + rstep + k0 + co, Asb + i*4096 + w*1024);
            gload_lds16(Brow0 + (size_t)rb*1536 + rstep + k0 + co, Bsb + i*4096 + w*1024);
        }
        __syncthreads();
        bf16x8 af[2][4], bfr[2][4];
        #pragma unroll
        for (int kk = 0; kk < 2; ++kk) {
            const int coff = (kk*64 + ((l >> 4) << 4)) ^ rsw;
            #pragma unroll
            for (int mi = 0; mi < 4; ++mi) {
                const int rowA = wr*64 + mi*16 + (l & 15);
                af[kk][mi]  = *(const bf16x8*)(Asb + rowA*128 + coff);
                const int rowB = wc*64 + mi*16 + (l & 15);
                bfr[kk][mi] = *(const bf16x8*)(Bsb + rowB*128 + coff);
            }
        }
        #pragma unroll
        for (int mi = 0; mi < 4; ++mi)
            #pragma unroll
            for (int nj = 0; nj < 4; ++nj) {
                acc[mi][nj] = __builtin_amdgcn_mfma_f32_16x16x32_bf16(
                                  af[0][mi], bfr[0][nj], acc[mi][nj], 0, 0, 0);
                acc[mi][nj] = __builtin_amdgcn_mfma_f32_16x16x32_bf16(
                                  af[1][mi], bfr[1][nj], acc[mi][nj], 0, 0, 0);
            }
        __syncthreads();
    }
}

// =======================================================================
// K0: q/v projection. xbf [16384][768] bf16, wqv [1536][768] bf16.
// bj<6 -> q cols (fp32 out, [bh][n][64]); bj>=6 -> v cols (bf16 out).
// =======================================================================
__global__ __launch_bounds__(256)
void gemm_qkv_mfma(const u16* __restrict__ xbf, const u16* __restrict__ wqv,
                   float* __restrict__ qbuf, u16* __restrict__ vbf)
{
    __shared__ u16 As[128*64];
    __shared__ u16 Bs[128*64];
    const int m0 = blockIdx.x * 128;
    const int bj = blockIdx.y;
    const int tid = threadIdx.x;
    f32x4 acc[4][4];
    #pragma unroll
    for (int i = 0; i < 4; ++i)
        #pragma unroll
        for (int j = 0; j < 4; ++j) acc[i][j] = (f32x4){0.f,0.f,0.f,0.f};

    mfma_gemm_core((const char*)xbf + (size_t)m0*1536,
                   (const char*)wqv + (size_t)bj*128*1536,
                   As, Bs, tid, acc);

    const int l = tid & 63, w = tid >> 6;
    const int wr = w >> 1, wc = w & 1;
    const int colb = (bj % 6)*128 + wc*64;
    const int rbase = m0 + wr*64 + ((l >> 4) << 2);
    if (bj < 6) {
        #pragma unroll
        for (int mi = 0; mi < 4; ++mi)
            #pragma unroll
            for (int nj = 0; nj < 4; ++nj) {
                const int col = colb + nj*16 + (l & 15);
                const int h = col >> 6, d = col & 63;
                #pragma unroll
                for (int rr = 0; rr < 4; ++rr) {
                    const int m = rbase + mi*16 + rr;
                    const int b_ = m >> 8, n_ = m & 255;
                    qbuf[((((size_t)b_*12 + h) << 8) + n_)*64 + d] = acc[mi][nj][rr];
                }
            }
    } else {
        #pragma unroll
        for (int mi = 0; mi < 4; ++mi)
            #pragma unroll
            for (int nj = 0; nj < 4; ++nj) {
                const int col = colb + nj*16 + (l & 15);
                const int h = col >> 6, d = col & 63;
                #pragma unroll
                for (int rr = 0; rr < 4; ++rr) {
                    const int m = rbase + mi*16 + rr;
                    const int b_ = m >> 8, n_ = m & 255;
                    vbf[((((size_t)b_*12 + h) << 8) + n_)*64 + d] = f2bf(acc[mi][nj][rr]);
                }
            }
    }
}

// =======================================================================
// K5: out = ctx @ w_proj^T + b_proj. ctxb [16384][768] bf16, wpb [768][768] bf16.
// =======================================================================
__global__ __launch_bounds__(256)
void gemm_proj_mfma(const u16* __restrict__ ctxb, const u16* __restrict__ wpb,
                    const float* __restrict__ bias, float* __restrict__ out)
{
    __shared__ u16 As[128*64];
    __shared__ u16 Bs[128*64];
    const int m0 = blockIdx.x * 128;
    const int n0 = blockIdx.y * 128;
    const int tid = threadIdx.x;
    f32x4 acc[4][4];
    #pragma unroll
    for (int i = 0; i < 4; ++i)
        #pragma unroll
        for (int j = 0; j < 4; ++j) acc[i][j] = (f32x4){0.f,0.f,0.f,0.f};

    mfma_gemm_core((const char*)ctxb + (size_t)m0*1536,
                   (const char*)wpb + (size_t)n0*1536,
                   As, Bs, tid, acc);

    const int l = tid & 63, w = tid >> 6;
    const int wr = w >> 1, wc = w & 1;
    const int rbase = m0 + wr*64 + ((l >> 4) << 2);
    #pragma unroll
    for (int mi = 0; mi < 4; ++mi)
        #pragma unroll
        for (int nj = 0; nj < 4; ++nj) {
            const int col = n0 + wc*64 + nj*16 + (l & 15);
            const float bv = bias[col];
            #pragma unroll
            for (int rr = 0; rr < 4; ++rr) {
                const int m = rbase + mi*16 + rr;
                out[(size_t)m*768 + col] = acc[mi][nj][rr] + bv;
            }
        }
}

// =======================================================================
// K1: normalize q rows in place: q /= (||q|| + 1e-8). One wave per row.
// =======================================================================
__global__ __launch_bounds__(256)
void normalize_kernel(float* __restrict__ q)
{
    const int row = blockIdx.x * 4 + (threadIdx.x >> 6);
    const int d   = threadIdx.x & 63;
    const size_t idx = (size_t)row * 64 + d;
    const float val = q[idx];
    float s = val * val;
    #pragma unroll
    for (int off = 32; off > 0; off >>= 1) s += __shfl_xor(s, off);
    q[idx] = val / (sqrtf(s) + 1e-8f);
}

// =======================================================================
// K2: K[n][m] = exp(10*cos(n,m) - 10) off-diag, 0 on diag. bf16 out.
// =======================================================================
__global__ __launch_bounds__(256)
void cost_kernel(const float* __restrict__ qn, u16* __restrict__ Kmat)
{
    __shared__ float Qak[64][128];
    __shared__ float Qbk[64][128];
    const int bh = blockIdx.y;
    const int tr = (blockIdx.x >> 1) * 128;
    const int tc = (blockIdx.x & 1) * 128;
    const float* qb = qn + (size_t)bh * (256 * 64);
    const int tid = threadIdx.x;
    const int tx = tid & 15, ty = tid >> 4;
    {
        const int r  = tid >> 1;            // 0..127
        const int kb = (tid & 1) * 32;
        #pragma unroll
        for (int qq = 0; qq < 8; ++qq) {
            const int k = kb + qq * 4;
            float4 a = *(const float4*)&qb[(size_t)(tr + r) * 64 + k];
            Qak[k+0][r] = a.x; Qak[k+1][r] = a.y; Qak[k+2][r] = a.z; Qak[k+3][r] = a.w;
            float4 b = *(const float4*)&qb[(size_t)(tc + r) * 64 + k];
            Qbk[k+0][r] = b.x; Qbk[k+1][r] = b.y; Qbk[k+2][r] = b.z; Qbk[k+3][r] = b.w;
        }
    }
    __syncthreads();
    float acc[8][8];
    #pragma unroll
    for (int i = 0; i < 8; ++i)
        #pragma unroll
        for (int j = 0; j < 8; ++j) acc[i][j] = 0.f;
    #pragma unroll 4
    for (int k = 0; k < 64; ++k) {
        float4 a0 = *(const float4*)&Qak[k][4*ty];
        float4 a1 = *(const float4*)&Qak[k][64 + 4*ty];
        float4 b0 = *(const float4*)&Qbk[k][4*tx];
        float4 b1 = *(const float4*)&Qbk[k][64 + 4*tx];
        float a[8] = {a0.x,a0.y,a0.z,a0.w,a1.x,a1.y,a1.z,a1.w};
        float b[8] = {b0.x,b0.y,b0.z,b0.w,b1.x,b1.y,b1.z,b1.w};
        #pragma unroll
        for (int i = 0; i < 8; ++i)
            #pragma unroll
            for (int j = 0; j < 8; ++j)
                acc[i][j] = fmaf(a[i], b[j], acc[i][j]);
    }
    u16* Kb = Kmat + (size_t)bh * 65536;
    #pragma unroll
    for (int rp = 0; rp < 2; ++rp)
        #pragma unroll
        for (int i = 0; i < 4; ++i) {
            const int gr = tr + rp*64 + 4*ty + i;
            #pragma unroll
            for (int cp = 0; cp < 2; ++cp) {
                const int gc0 = tc + cp*64 + 4*tx;
                float km[4];
                #pragma unroll
                for (int j = 0; j < 4; ++j) {
                    const float s = acc[rp*4+i][cp*4+j];
                    km[j] = (gr == gc0 + j) ? 0.f : __expf(fmaf(10.f, s, -10.f));
                }
                *(uint2*)&Kb[(size_t)gr * 256 + gc0] =
                    make_uint2(pack2bf(km[0], km[1]), pack2bf(km[2], km[3]));
            }
        }
}

// =======================================================================
// K3: exp-domain Sinkhorn, one block per (b,h), K staged in LDS (128 KB).
// 512 threads: t=tid&31 owns cols 8t..8t+7, g=tid>>5 owns rows 16g..16g+15.
// K symmetric -> both half-updates are column-sums. 20 matvecs + Tmax,
// all K reads from LDS (HBM touched exactly once).
// =======================================================================
__global__ __launch_bounds__(512)
void sinkhorn_kernel(const u16* __restrict__ Kmat, float* __restrict__ ubuf,
                     float* __restrict__ vbuf, float* __restrict__ tmaxbuf)
{
    __shared__ u16   Ks[256*256];    // 128 KB
    __shared__ float part[16][256];  // 16 KB
    __shared__ float xv[256];
    __shared__ float usave[256];
    const int bh  = blockIdx.x;
    const int tid = threadIdx.x;
    const int t = tid & 31;          // owns cols 8t..8t+7
    const int g = tid >> 5;          // owns rows g*16..g*16+15

    // ---- stage K into LDS: 131072 B, 16 issues x (512 thr x 16 B)
    {
        const char* src = (const char*)(Kmat + (size_t)bh * 65536);
        char* dst = (char*)Ks;
        const int w = tid >> 6;                    // wave 0..7 (uniform)
        const int loff = (tid & 63) * 16;
        #pragma unroll
        for (int i = 0; i < 16; ++i) {
            gload_lds16(src + i*8192 + w*1024 + loff, dst + i*8192 + w*1024);
        }
    }
    if (tid < 256) xv[tid] = 1.0f;
    __syncthreads();                 // drains vmcnt -> K resident

    for (int it = 0; it < 20; ++it) {
        float y[8] = {0,0,0,0,0,0,0,0};
        #pragma unroll 4
        for (int nn = 0; nn < 16; ++nn) {
            const int n = g * 16 + nn;
            const uint4 raw = *(const uint4*)&Ks[n * 256 + t * 8];
            const float xn = xv[n];
            y[0] = fmaf(bf2f((u16)(raw.x & 0xffffu)), xn, y[0]);
            y[1] = fmaf(bf2f((u16)(raw.x >> 16)),     xn, y[1]);
            y[2] = fmaf(bf2f((u16)(raw.y & 0xffffu)), xn, y[2]);
            y[3] = fmaf(bf2f((u16)(raw.y >> 16)),     xn, y[3]);
            y[4] = fmaf(bf2f((u16)(raw.z & 0xffffu)), xn, y[4]);
            y[5] = fmaf(bf2f((u16)(raw.z >> 16)),     xn, y[5]);
            y[6] = fmaf(bf2f((u16)(raw.w & 0xffffu)), xn, y[6]);
            y[7] = fmaf(bf2f((u16)(raw.w >> 16)),     xn, y[7]);
        }
        *(float4*)&part[g][t*8]     = make_float4(y[0], y[1], y[2], y[3]);
        *(float4*)&part[g][t*8 + 4] = make_float4(y[4], y[5], y[6], y[7]);
        __syncthreads();
        if (tid < 256) {
            float s = 0.f;
            #pragma unroll
            for (int gg = 0; gg < 16; ++gg) s += part[gg][tid];
            const float xn = 0.00390625f / s;       // (1/256)/s
            if (it == 18) usave[tid] = xn;          // last u-update
            xv[tid] = xn;
        }
        __syncthreads();
    }
    // Tmax = max over (n,m) of u[n]*K[n][m]*v[m]
    float vx[8];
    #pragma unroll
    for (int q = 0; q < 8; ++q) vx[q] = xv[t*8 + q];
    float mx = 0.f;
    #pragma unroll 4
    for (int nn = 0; nn < 16; ++nn) {
        const int n = g * 16 + nn;
        const uint4 raw = *(const uint4*)&Ks[n * 256 + t * 8];
        const float un = usave[n];
        mx = fmaxf(mx, un * bf2f((u16)(raw.x & 0xffffu)) * vx[0]);
        mx = fmaxf(mx, un * bf2f((u16)(raw.x >> 16))     * vx[1]);
        mx = fmaxf(mx, un * bf2f((u16)(raw.y & 0xffffu)) * vx[2]);
        mx = fmaxf(mx, un * bf2f((u16)(raw.y >> 16))     * vx[3]);
        mx = fmaxf(mx, un * bf2f((u16)(raw.z & 0xffffu)) * vx[4]);
        mx = fmaxf(mx, un * bf2f((u16)(raw.z >> 16))     * vx[5]);
        mx = fmaxf(mx, un * bf2f((u16)(raw.w & 0xffffu)) * vx[6]);
        mx = fmaxf(mx, un * bf2f((u16)(raw.w >> 16))     * vx[7]);
    }
    float* pf = &part[0][0];
    pf[tid] = mx;
    __syncthreads();
    for (int sft = 256; sft > 0; sft >>= 1) {
        if (tid < sft) pf[tid] = fmaxf(pf[tid], pf[tid + sft]);
        __syncthreads();
    }
    if (tid < 256) {
        ubuf[bh * 256 + tid] = usave[tid];
        vbuf[bh * 256 + tid] = xv[tid];
    }
    if (tid == 0) tmaxbuf[bh] = pf[0];
}

// =======================================================================
// K4: per (b,h): z = u*K*v/Tmax (diag=1), p = exp(z*0.125), PV, late
// row-sum division. attnT bf16 swizzled in LDS; V bf16 direct copy.
// ctx written as bf16 [b][n][768] for the proj MFMA GEMM.
// =======================================================================
__global__ __launch_bounds__(256)
void softpv_kernel(const u16* __restrict__ Kmat, const u16* __restrict__ vbf,
                   const float* __restrict__ ubuf, const float* __restrict__ vbuf,
                   const float* __restrict__ tmaxbuf, u16* __restrict__ ctxc)
{
    __shared__ u16 attnT[64][256];   // [m_local][n ^ swz]
    __shared__ u16 Vs[256][64];      // [m][d] bf16
    const int bh = blockIdx.x;
    const int b_ = bh / 12, h_ = bh % 12;
    const u16* Km = Kmat + (size_t)bh * 65536;
    const float* ub = ubuf + bh * 256;
    const float* vb = vbuf + bh * 256;
    const int tid  = threadIdx.x;
    const int lane = tid & 63, w = tid >> 6;
    const int tx = tid & 15,  ty = tid >> 4;
    const float itmax = 1.0f / tmaxbuf[bh];
    {
        const uint4* Vg4 = (const uint4*)(vbf + (size_t)bh * 16384);
        uint4* Vs4 = (uint4*)&Vs[0][0];
        #pragma unroll
        for (int p = 0; p < 8; ++p) Vs4[p*256 + tid] = Vg4[p*256 + tid];
    }
    float acc[4][4][4] = {};
    float psum_reg = 0.f;
    const int swz = (lane & 15) << 2;
    __syncthreads();
    for (int mc = 0; mc < 4; ++mc) {
        const int m = mc * 64 + lane;
        const float vm = vb[m];
        for (int rr = 0; rr < 64; ++rr) {
            const int n = w * 64 + rr;
            const float un = ub[n];
            const float kmv = bf2f(Km[(size_t)n * 256 + m]);
            float z = un * kmv * vm * itmax;
            if (m == n) z = 1.0f;
            const u16 pb = f2bf(__expf(z * 0.125f));
            attnT[lane][n ^ swz] = pb;
            float r = bf2f(pb);
            #pragma unroll
            for (int off = 1; off < 64; off <<= 1) r += __shfl_xor(r, off);
            if (lane == rr) psum_reg += r;
        }
        __syncthreads();
        #pragma unroll 2
        for (int k = 0; k < 64; ++k) {
            const uint2 vp = *(const uint2*)&Vs[mc * 64 + k][4 * tx];
            float bvv[4];
            bvv[0] = bf2f((u16)(vp.x & 0xffffu)); bvv[1] = bf2f((u16)(vp.x >> 16));
            bvv[2] = bf2f((u16)(vp.y & 0xffffu)); bvv[3] = bf2f((u16)(vp.y >> 16));
            const int ksw = (k & 15) << 2;
            #pragma unroll
            for (int rp = 0; rp < 4; ++rp) {
                const int coff = (rp * 64 + 4 * ty) ^ ksw;
                const uint2 ap = *(const uint2*)&attnT[k][coff];
                float av[4];
                av[0] = bf2f((u16)(ap.x & 0xffffu)); av[1] = bf2f((u16)(ap.x >> 16));
                av[2] = bf2f((u16)(ap.y & 0xffffu)); av[3] = bf2f((u16)(ap.y >> 16));
                #pragma unroll
                for (int i = 0; i < 4; ++i)
                    #pragma unroll
                    for (int j = 0; j < 4; ++j)
                        acc[rp][i][j] = fmaf(av[i], bvv[j], acc[rp][i][j]);
            }
        }
        __syncthreads();
    }
    float* psf = (float*)&attnT[0][0];
    psf[w * 64 + lane] = psum_reg;
    __syncthreads();
    #pragma unroll
    for (int rp = 0; rp < 4; ++rp)
        #pragma unroll
        for (int i = 0; i < 4; ++i) {
            const int n = rp * 64 + 4 * ty + i;
            const float inv = 1.0f / psf[n];
            *(uint2*)&ctxc[((size_t)b_ * 256 + n) * 768 + h_ * 64 + 4 * tx] =
                make_uint2(pack2bf(acc[rp][i][0] * inv, acc[rp][i][1] * inv),
                           pack2bf(acc[rp][i][2] * inv, acc[rp][i][3] * inv));
        }
}

// =======================================================================
extern "C" void kernel_launch(void* const* d_in, const int* in_sizes, int n_in,
                              void* d_out, int out_size, void* d_ws, size_t ws_size,
                              hipStream_t stream)
{
    (void)in_sizes; (void)n_in; (void)out_size; (void)ws_size;
    const float* x      = (const float*)d_in[0];
    const float* w_qkv  = (const float*)d_in[1];
    const float* w_proj = (const float*)d_in[2];
    const float* b_proj = (const float*)d_in[3];
    float* out = (float*)d_out;

    char* w = (char*)d_ws;
    // workspace layout (bytes):
    u16*   xbf  = (u16*)  (w);                     //  25,165,824  x bf16 [16384][768]
    u16*   wqv  = (u16*)  (w + 25165824);          //   2,359,296  w q+v rows bf16 [1536][768]
    u16*   wpb  = (u16*)  (w + 27525120);          //   1,179,648  w_proj bf16 [768][768]
    float* qbuf = (float*)(w + 28704768);          //  50,331,648  q fp32 [768][256][64]
    u16*   vbf  = (u16*)  (w + 79036416);          //  25,165,824  v bf16 [768][256][64]
    u16*   ctxc = (u16*)  (w + 104202240);         //  25,165,824  ctx bf16 [64][256][768]
    float* ub   = (float*)(w + 129368064);         //     786,432  u [768][256]
    float* vb   = (float*)(w + 130154496);         //     786,432  v [768][256]
    float* tmx  = (float*)(w + 130940928);         //       3,072  tmax [768]
    u16*   Km   = (u16*)  (w + 130944000);         // 100,663,296  K bf16 [768][256][256]
    // total ~231.6 MB

    conv_bf16       <<<dim3(6144),    256, 0, stream>>>(x, xbf, 1572864);
    conv_wqv        <<<dim3(576),     256, 0, stream>>>(w_qkv, wqv);
    conv_bf16       <<<dim3(288),     256, 0, stream>>>(w_proj, wpb, 73728);
    gemm_qkv_mfma   <<<dim3(128, 12), 256, 0, stream>>>(xbf, wqv, qbuf, vbf);
    normalize_kernel<<<dim3(49152),   256, 0, stream>>>(qbuf);
    cost_kernel     <<<dim3(4, 768),  256, 0, stream>>>(qbuf, Km);
    sinkhorn_kernel <<<dim3(768),     512, 0, stream>>>(Km, ub, vb, tmx);
    softpv_kernel   <<<dim3(768),     256, 0, stream>>>(Km, vbf, ub, vb, tmx, ctxc);
    gemm_proj_mfma  <<<dim3(128, 6),  256, 0, stream>>>(ctxc, wpb, b_proj, out);
}

// Round 4
// 353.113 us; speedup vs baseline: 3.6051x; 1.4869x over previous
//
#include <hip/hip_runtime.h>

typedef unsigned short u16;
typedef unsigned int   u32;
typedef __attribute__((ext_vector_type(8))) short bf16x8;
typedef __attribute__((ext_vector_type(4))) float f32x4;

// ---------- bf16 helpers (manual, RNE) ----------
__device__ __forceinline__ u16 f2bf(float f) {
    u32 u = __float_as_uint(f);
    u += 0x7fffu + ((u >> 16) & 1u);
    return (u16)(u >> 16);
}
__device__ __forceinline__ float bf2f(u16 s) {
    return __uint_as_float(((u32)s) << 16);
}
__device__ __forceinline__ u32 pack2bf(float f0, float f1) {
    return (u32)f2bf(f0) | ((u32)f2bf(f1) << 16);
}

__device__ __forceinline__ void gload_lds16(const void* g, void* l) {
    __builtin_amdgcn_global_load_lds(
        (const __attribute__((address_space(1))) u32*)g,
        (__attribute__((address_space(3))) u32*)l, 16, 0, 0);
}

// =======================================================================
// fp32 -> bf16 converters
// =======================================================================
__global__ __launch_bounds__(256)
void conv_bf16(const float* __restrict__ src, u16* __restrict__ dst, int n8)
{
    const int i = blockIdx.x * 256 + threadIdx.x;   // 8 elements per thread
    if (i < n8) {
        const float4 a = ((const float4*)src)[2*i];
        const float4 b = ((const float4*)src)[2*i + 1];
        ((uint4*)dst)[i] = make_uint4(pack2bf(a.x,a.y), pack2bf(a.z,a.w),
                                      pack2bf(b.x,b.y), pack2bf(b.z,b.w));
    }
}

// w_qkv [2304][768]: keep q rows 0..767 and v rows 1536..2303 -> wqv [1536][768]
__global__ __launch_bounds__(256)
void conv_wqv(const float* __restrict__ w, u16* __restrict__ dst)
{
    const int i = blockIdx.x * 256 + threadIdx.x;   // chunk of 8, 96 chunks/row
    const int row = i / 96;
    const int cc  = (i - row * 96) * 8;
    const int srow = row + (row >= 768 ? 768 : 0);
    const float4 a = *(const float4*)&w[(size_t)srow*768 + cc];
    const float4 b = *(const float4*)&w[(size_t)srow*768 + cc + 4];
    *(uint4*)&dst[(size_t)row*768 + cc] =
        make_uint4(pack2bf(a.x,a.y), pack2bf(a.z,a.w), pack2bf(b.x,b.y), pack2bf(b.z,b.w));
}

// =======================================================================
// Shared MFMA GEMM core: C[128x128] tile, K=768, bf16 A[.,768] x B[.,768]^T.
// BK=64, 4 waves (2x2), 16x16x32 MFMA, global_load_lds + XOR-swizzled LDS.
// =======================================================================
__device__ __forceinline__ void mfma_gemm_core(
    const char* __restrict__ Arow0,   // &A[m0][0] as bytes (row stride 1536)
    const char* __restrict__ Brow0,   // &B[n0][0] as bytes
    u16* As, u16* Bs, const int tid, f32x4 acc[4][4])
{
    const int l  = tid & 63, w = tid >> 6;
    const int wr = w >> 1,  wc = w & 1;
    char* Asb = (char*)As;
    char* Bsb = (char*)Bs;
    const int co = 16 * ((l & 7) ^ (l >> 3));       // swizzled global byte col
    const size_t rstep = (size_t)(l >> 3) * 1536;
    const int rsw = (l & 7) << 4;                   // read-side XOR

    for (int k0 = 0; k0 < 1536; k0 += 128) {        // 12 K-steps of 64 bf16
        #pragma unroll
        for (int i = 0; i < 4; ++i) {
            const int rb = i*32 + w*8;
            gload_lds16(Arow0 + (size_t)rb*1536 + rstep + k0 + co, Asb + i*4096 + w*1024);
            gload_lds16(Brow0 + (size_t)rb*1536 + rstep + k0 + co, Bsb + i*4096 + w*1024);
        }
        __syncthreads();
        bf16x8 af[2][4], bfr[2][4];
        #pragma unroll
        for (int kk = 0; kk < 2; ++kk) {
            const int coff = (kk*64 + ((l >> 4) << 4)) ^ rsw;
            #pragma unroll
            for (int mi = 0; mi < 4; ++mi) {
                const int rowA = wr*64 + mi*16 + (l & 15);
                af[kk][mi]  = *(const bf16x8*)(Asb + rowA*128 + coff);
                const int rowB = wc*64 + mi*16 + (l & 15);
                bfr[kk][mi] = *(const bf16x8*)(Bsb + rowB*128 + coff);
            }
        }
        #pragma unroll
        for (int mi = 0; mi < 4; ++mi)
            #pragma unroll
            for (int nj = 0; nj < 4; ++nj) {
                acc[mi][nj] = __builtin_amdgcn_mfma_f32_16x16x32_bf16(
                                  af[0][mi], bfr[0][nj], acc[mi][nj], 0, 0, 0);
                acc[mi][nj] = __builtin_amdgcn_mfma_f32_16x16x32_bf16(
                                  af[1][mi], bfr[1][nj], acc[mi][nj], 0, 0, 0);
            }
        __syncthreads();
    }
}

// =======================================================================
// K0: q/v projection. xbf [16384][768] bf16, wqv [1536][768] bf16.
// bj<6 -> q cols (fp32 out, [bh][n][64]); bj>=6 -> v cols, written
// TRANSPOSED as vbfT [bh][d=64][m=256] bf16 for softpv's Vt staging.
// =======================================================================
__global__ __launch_bounds__(256)
void gemm_qkv_mfma(const u16* __restrict__ xbf, const u16* __restrict__ wqv,
                   float* __restrict__ qbuf, u16* __restrict__ vbfT)
{
    __shared__ u16 As[128*64];
    __shared__ u16 Bs[128*64];
    const int m0 = blockIdx.x * 128;
    const int bj = blockIdx.y;
    const int tid = threadIdx.x;
    f32x4 acc[4][4];
    #pragma unroll
    for (int i = 0; i < 4; ++i)
        #pragma unroll
        for (int j = 0; j < 4; ++j) acc[i][j] = (f32x4){0.f,0.f,0.f,0.f};

    mfma_gemm_core((const char*)xbf + (size_t)m0*1536,
                   (const char*)wqv + (size_t)bj*128*1536,
                   As, Bs, tid, acc);

    const int l = tid & 63, w = tid >> 6;
    const int wr = w >> 1, wc = w & 1;
    const int colb = (bj % 6)*128 + wc*64;
    const int rbase = m0 + wr*64 + ((l >> 4) << 2);
    if (bj < 6) {
        #pragma unroll
        for (int mi = 0; mi < 4; ++mi)
            #pragma unroll
            for (int nj = 0; nj < 4; ++nj) {
                const int col = colb + nj*16 + (l & 15);
                const int h = col >> 6, d = col & 63;
                #pragma unroll
                for (int rr = 0; rr < 4; ++rr) {
                    const int m = rbase + mi*16 + rr;
                    const int b_ = m >> 8, n_ = m & 255;
                    qbuf[((((size_t)b_*12 + h) << 8) + n_)*64 + d] = acc[mi][nj][rr];
                }
            }
    } else {
        #pragma unroll
        for (int mi = 0; mi < 4; ++mi)
            #pragma unroll
            for (int nj = 0; nj < 4; ++nj) {
                const int col = colb + nj*16 + (l & 15);
                const int h = col >> 6, d = col & 63;
                const int m = rbase + mi*16;        // rows m..m+3 (consecutive)
                const int b_ = m >> 8, n_ = m & 255;
                uint2 o = make_uint2(pack2bf(acc[mi][nj][0], acc[mi][nj][1]),
                                     pack2bf(acc[mi][nj][2], acc[mi][nj][3]));
                *(uint2*)&vbfT[(((size_t)b_*12 + h)*64 + d)*256 + n_] = o;
            }
    }
}

// =======================================================================
// K5: out = ctx @ w_proj^T + b_proj. ctxb [16384][768] bf16, wpb [768][768] bf16.
// =======================================================================
__global__ __launch_bounds__(256)
void gemm_proj_mfma(const u16* __restrict__ ctxb, const u16* __restrict__ wpb,
                    const float* __restrict__ bias, float* __restrict__ out)
{
    __shared__ u16 As[128*64];
    __shared__ u16 Bs[128*64];
    const int m0 = blockIdx.x * 128;
    const int n0 = blockIdx.y * 128;
    const int tid = threadIdx.x;
    f32x4 acc[4][4];
    #pragma unroll
    for (int i = 0; i < 4; ++i)
        #pragma unroll
        for (int j = 0; j < 4; ++j) acc[i][j] = (f32x4){0.f,0.f,0.f,0.f};

    mfma_gemm_core((const char*)ctxb + (size_t)m0*1536,
                   (const char*)wpb + (size_t)n0*1536,
                   As, Bs, tid, acc);

    const int l = tid & 63, w = tid >> 6;
    const int wr = w >> 1, wc = w & 1;
    const int rbase = m0 + wr*64 + ((l >> 4) << 2);
    #pragma unroll
    for (int mi = 0; mi < 4; ++mi)
        #pragma unroll
        for (int nj = 0; nj < 4; ++nj) {
            const int col = n0 + wc*64 + nj*16 + (l & 15);
            const float bv = bias[col];
            #pragma unroll
            for (int rr = 0; rr < 4; ++rr) {
                const int m = rbase + mi*16 + rr;
                out[(size_t)m*768 + col] = acc[mi][nj][rr] + bv;
            }
        }
}

// =======================================================================
// K1: normalize q rows in place: q /= (||q|| + 1e-8). One wave per row.
// =======================================================================
__global__ __launch_bounds__(256)
void normalize_kernel(float* __restrict__ q)
{
    const int row = blockIdx.x * 4 + (threadIdx.x >> 6);
    const int d   = threadIdx.x & 63;
    const size_t idx = (size_t)row * 64 + d;
    const float val = q[idx];
    float s = val * val;
    #pragma unroll
    for (int off = 32; off > 0; off >>= 1) s += __shfl_xor(s, off);
    q[idx] = val / (sqrtf(s) + 1e-8f);
}

// =======================================================================
// K2: K[n][m] = exp(10*cos(n,m) - 10) off-diag, 0 on diag. bf16 out.
// =======================================================================
__global__ __launch_bounds__(256)
void cost_kernel(const float* __restrict__ qn, u16* __restrict__ Kmat)
{
    __shared__ float Qak[64][128];
    __shared__ float Qbk[64][128];
    const int bh = blockIdx.y;
    const int tr = (blockIdx.x >> 1) * 128;
    const int tc = (blockIdx.x & 1) * 128;
    const float* qb = qn + (size_t)bh * (256 * 64);
    const int tid = threadIdx.x;
    const int tx = tid & 15, ty = tid >> 4;
    {
        const int r  = tid >> 1;            // 0..127
        const int kb = (tid & 1) * 32;
        #pragma unroll
        for (int qq = 0; qq < 8; ++qq) {
            const int k = kb + qq * 4;
            float4 a = *(const float4*)&qb[(size_t)(tr + r) * 64 + k];
            Qak[k+0][r] = a.x; Qak[k+1][r] = a.y; Qak[k+2][r] = a.z; Qak[k+3][r] = a.w;
            float4 b = *(const float4*)&qb[(size_t)(tc + r) * 64 + k];
            Qbk[k+0][r] = b.x; Qbk[k+1][r] = b.y; Qbk[k+2][r] = b.z; Qbk[k+3][r] = b.w;
        }
    }
    __syncthreads();
    float acc[8][8];
    #pragma unroll
    for (int i = 0; i < 8; ++i)
        #pragma unroll
        for (int j = 0; j < 8; ++j) acc[i][j] = 0.f;
    #pragma unroll 4
    for (int k = 0; k < 64; ++k) {
        float4 a0 = *(const float4*)&Qak[k][4*ty];
        float4 a1 = *(const float4*)&Qak[k][64 + 4*ty];
        float4 b0 = *(const float4*)&Qbk[k][4*tx];
        float4 b1 = *(const float4*)&Qbk[k][64 + 4*tx];
        float a[8] = {a0.x,a0.y,a0.z,a0.w,a1.x,a1.y,a1.z,a1.w};
        float b[8] = {b0.x,b0.y,b0.z,b0.w,b1.x,b1.y,b1.z,b1.w};
        #pragma unroll
        for (int i = 0; i < 8; ++i)
            #pragma unroll
            for (int j = 0; j < 8; ++j)
                acc[i][j] = fmaf(a[i], b[j], acc[i][j]);
    }
    u16* Kb = Kmat + (size_t)bh * 65536;
    #pragma unroll
    for (int rp = 0; rp < 2; ++rp)
        #pragma unroll
        for (int i = 0; i < 4; ++i) {
            const int gr = tr + rp*64 + 4*ty + i;
            #pragma unroll
            for (int cp = 0; cp < 2; ++cp) {
                const int gc0 = tc + cp*64 + 4*tx;
                float km[4];
                #pragma unroll
                for (int j = 0; j < 4; ++j) {
                    const float s = acc[rp*4+i][cp*4+j];
                    km[j] = (gr == gc0 + j) ? 0.f : __expf(fmaf(10.f, s, -10.f));
                }
                *(uint2*)&Kb[(size_t)gr * 256 + gc0] =
                    make_uint2(pack2bf(km[0], km[1]), pack2bf(km[2], km[3]));
            }
        }
}

// =======================================================================
// K3: exp-domain Sinkhorn, one block per (b,h), K staged in LDS (128 KB).
// =======================================================================
__global__ __launch_bounds__(512)
void sinkhorn_kernel(const u16* __restrict__ Kmat, float* __restrict__ ubuf,
                     float* __restrict__ vbuf, float* __restrict__ tmaxbuf)
{
    __shared__ u16   Ks[256*256];    // 128 KB
    __shared__ float part[16][256];  // 16 KB
    __shared__ float xv[256];
    __shared__ float usave[256];
    const int bh  = blockIdx.x;
    const int tid = threadIdx.x;
    const int t = tid & 31;          // owns cols 8t..8t+7
    const int g = tid >> 5;          // owns rows g*16..g*16+15

    {
        const char* src = (const char*)(Kmat + (size_t)bh * 65536);
        char* dst = (char*)Ks;
        const int w = tid >> 6;                    // wave 0..7 (uniform)
        const int loff = (tid & 63) * 16;
        #pragma unroll
        for (int i = 0; i < 16; ++i) {
            gload_lds16(src + i*8192 + w*1024 + loff, dst + i*8192 + w*1024);
        }
    }
    if (tid < 256) xv[tid] = 1.0f;
    __syncthreads();                 // drains vmcnt -> K resident

    for (int it = 0; it < 20; ++it) {
        float y[8] = {0,0,0,0,0,0,0,0};
        #pragma unroll 4
        for (int nn = 0; nn < 16; ++nn) {
            const int n = g * 16 + nn;
            const uint4 raw = *(const uint4*)&Ks[n * 256 + t * 8];
            const float xn = xv[n];
            y[0] = fmaf(bf2f((u16)(raw.x & 0xffffu)), xn, y[0]);
            y[1] = fmaf(bf2f((u16)(raw.x >> 16)),     xn, y[1]);
            y[2] = fmaf(bf2f((u16)(raw.y & 0xffffu)), xn, y[2]);
            y[3] = fmaf(bf2f((u16)(raw.y >> 16)),     xn, y[3]);
            y[4] = fmaf(bf2f((u16)(raw.z & 0xffffu)), xn, y[4]);
            y[5] = fmaf(bf2f((u16)(raw.z >> 16)),     xn, y[5]);
            y[6] = fmaf(bf2f((u16)(raw.w & 0xffffu)), xn, y[6]);
            y[7] = fmaf(bf2f((u16)(raw.w >> 16)),     xn, y[7]);
        }
        *(float4*)&part[g][t*8]     = make_float4(y[0], y[1], y[2], y[3]);
        *(float4*)&part[g][t*8 + 4] = make_float4(y[4], y[5], y[6], y[7]);
        __syncthreads();
        if (tid < 256) {
            float s = 0.f;
            #pragma unroll
            for (int gg = 0; gg < 16; ++gg) s += part[gg][tid];
            const float xn = 0.00390625f / s;       // (1/256)/s
            if (it == 18) usave[tid] = xn;          // last u-update
            xv[tid] = xn;
        }
        __syncthreads();
    }
    float vx[8];
    #pragma unroll
    for (int q = 0; q < 8; ++q) vx[q] = xv[t*8 + q];
    float mx = 0.f;
    #pragma unroll 4
    for (int nn = 0; nn < 16; ++nn) {
        const int n = g * 16 + nn;
        const uint4 raw = *(const uint4*)&Ks[n * 256 + t * 8];
        const float un = usave[n];
        mx = fmaxf(mx, un * bf2f((u16)(raw.x & 0xffffu)) * vx[0]);
        mx = fmaxf(mx, un * bf2f((u16)(raw.x >> 16))     * vx[1]);
        mx = fmaxf(mx, un * bf2f((u16)(raw.y & 0xffffu)) * vx[2]);
        mx = fmaxf(mx, un * bf2f((u16)(raw.y >> 16))     * vx[3]);
        mx = fmaxf(mx, un * bf2f((u16)(raw.z & 0xffffu)) * vx[4]);
        mx = fmaxf(mx, un * bf2f((u16)(raw.z >> 16))     * vx[5]);
        mx = fmaxf(mx, un * bf2f((u16)(raw.w & 0xffffu)) * vx[6]);
        mx = fmaxf(mx, un * bf2f((u16)(raw.w >> 16))     * vx[7]);
    }
    float* pf = &part[0][0];
    pf[tid] = mx;
    __syncthreads();
    for (int sft = 256; sft > 0; sft >>= 1) {
        if (tid < sft) pf[tid] = fmaxf(pf[tid], pf[tid + sft]);
        __syncthreads();
    }
    if (tid < 256) {
        ubuf[bh * 256 + tid] = usave[tid];
        vbuf[bh * 256 + tid] = xv[tid];
    }
    if (tid == 0) tmaxbuf[bh] = pf[0];
}

// =======================================================================
// K4 (rewritten): per (b,h), 256 threads / 4 waves.
//  - thread n computes P row n in 4 chunks of 64: p = exp(a_n*K[n][m]*v[m]),
//    diag -> exp(0.125); row-sum S[n] accumulated in-register (no reduce).
//  - P-chunk written to LDS [256][64] bf16, XOR-swizzled (^(n&7) per 16B slot).
//  - PV via MFMA operand-swap: D = V^T P^T; A-frag = Vt rows (d, along m),
//    B-frag = P rows (n, along m). Wave w owns n in [w*64, w*64+64): all
//    LDS deps intra-wave -> NO per-chunk barriers.
//  - Vt [64][256] staged once via gload_lds16 with inverse-swizzled source.
//  - epilogue: d runs along acc regs -> uint2 ctx writes.
// =======================================================================
__global__ __launch_bounds__(256)
void softpv_kernel(const u16* __restrict__ Kmat, const u16* __restrict__ vbfT,
                   const float* __restrict__ ubuf, const float* __restrict__ vbuf,
                   const float* __restrict__ tmaxbuf, u16* __restrict__ ctxc)
{
    __shared__ u16 Vt[64*256];     // [d][m] bf16, swizzled: slot s holds global slot s^(d&7)
    __shared__ u16 Pl[256*64];     // [n][m-chunk] bf16, swizzled: slot i at i^(n&7)
    __shared__ float vmf[256];
    __shared__ float sinv[256];
    const int bh = blockIdx.x;
    const int b_ = bh / 12, h_ = bh - b_*12;
    const int tid = threadIdx.x;
    const int l = tid & 63, w = tid >> 6;

    // ---- stage Vt (32 KB): 8 issues x (256 thr x 16B); source pre-swizzled
    {
        const char* src = (const char*)(vbfT + (size_t)bh * 16384);
        char* dst = (char*)Vt;
        const int s = l & 31;                      // 16B slot within 512B row
        #pragma unroll
        for (int i = 0; i < 8; ++i) {
            const int d = i*8 + w*2 + (l >> 5);
            gload_lds16(src + d*512 + ((s ^ (d & 7)) << 4), dst + i*4096 + w*1024);
        }
    }
    vmf[tid] = vbuf[bh*256 + tid];
    const float an = ubuf[bh*256 + tid] * (1.0f / tmaxbuf[bh]) * 0.125f;
    const u16* Krow = Kmat + (size_t)bh*65536 + (size_t)tid*256;
    __syncthreads();                               // Vt + vmf resident

    f32x4 acc[4][4];                               // [mi=d-frag][nj=n-frag]
    #pragma unroll
    for (int i = 0; i < 4; ++i)
        #pragma unroll
        for (int j = 0; j < 4; ++j) acc[i][j] = (f32x4){0.f,0.f,0.f,0.f};
    float psum = 0.f;
    char* prow = (char*)Pl + tid*128;
    const int nsw = tid & 7;

    #pragma unroll
    for (int mc = 0; mc < 4; ++mc) {
        // ---- P row chunk: 8 x uint4 K loads, exp, pack, swizzled ds_write
        const uint4* kr = (const uint4*)(Krow + mc*64);
        #pragma unroll
        for (int i = 0; i < 8; ++i) {
            const uint4 raw = kr[i];
            const float4 va = *(const float4*)&vmf[mc*64 + i*8];
            const float4 vbq = *(const float4*)&vmf[mc*64 + i*8 + 4];
            float p[8];
            p[0] = __expf(an * bf2f((u16)(raw.x & 0xffffu)) * va.x);
            p[1] = __expf(an * bf2f((u16)(raw.x >> 16))     * va.y);
            p[2] = __expf(an * bf2f((u16)(raw.y & 0xffffu)) * va.z);
            p[3] = __expf(an * bf2f((u16)(raw.y >> 16))     * va.w);
            p[4] = __expf(an * bf2f((u16)(raw.z & 0xffffu)) * vbq.x);
            p[5] = __expf(an * bf2f((u16)(raw.z >> 16))     * vbq.y);
            p[6] = __expf(an * bf2f((u16)(raw.w & 0xffffu)) * vbq.z);
            p[7] = __expf(an * bf2f((u16)(raw.w >> 16))     * vbq.w);
            const int dj = tid - mc*64 - i*8;      // diagonal override
            if (dj >= 0 && dj < 8) p[dj] = 1.13314845f;   // exp(0.125)
            psum += ((p[0]+p[1]) + (p[2]+p[3])) + ((p[4]+p[5]) + (p[6]+p[7]));
            uint4 pw = make_uint4(pack2bf(p[0],p[1]), pack2bf(p[2],p[3]),
                                  pack2bf(p[4],p[5]), pack2bf(p[6],p[7]));
            *(uint4*)(prow + ((i ^ nsw) << 4)) = pw;
        }
        // ---- MFMA: D[d][n] += Vt[d][m-chunk] * P[n][m-chunk]
        #pragma unroll
        for (int kk = 0; kk < 2; ++kk) {
            bf16x8 afr[4], bfr[4];
            const int kb = kk*64 + ((l >> 4) << 4);
            #pragma unroll
            for (int f = 0; f < 4; ++f) {
                const int d = f*16 + (l & 15);
                afr[f] = *(const bf16x8*)((char*)Vt + d*512 + ((mc*128 + kb) ^ ((d & 7) << 4)));
                const int n = w*64 + f*16 + (l & 15);
                bfr[f] = *(const bf16x8*)((char*)Pl + n*128 + (kb ^ ((n & 7) << 4)));
            }
            #pragma unroll
            for (int mi = 0; mi < 4; ++mi)
                #pragma unroll
                for (int nj = 0; nj < 4; ++nj)
                    acc[mi][nj] = __builtin_amdgcn_mfma_f32_16x16x32_bf16(
                                      afr[mi], bfr[nj], acc[mi][nj], 0, 0, 0);
        }
    }
    sinv[tid] = 1.0f / psum;
    __syncthreads();
    // ---- epilogue: lane col = n, regs rr -> d consecutive
    u16* outp = ctxc + ((size_t)b_*256)*768 + h_*64;
    #pragma unroll
    for (int nj = 0; nj < 4; ++nj) {
        const int n = w*64 + nj*16 + (l & 15);
        const float is = sinv[n];
        #pragma unroll
        for (int mi = 0; mi < 4; ++mi) {
            const int d0 = mi*16 + ((l >> 4) << 2);
            uint2 o = make_uint2(pack2bf(acc[mi][nj][0]*is, acc[mi][nj][1]*is),
                                 pack2bf(acc[mi][nj][2]*is, acc[mi][nj][3]*is));
            *(uint2*)&outp[(size_t)n*768 + d0] = o;
        }
    }
}

// =======================================================================
extern "C" void kernel_launch(void* const* d_in, const int* in_sizes, int n_in,
                              void* d_out, int out_size, void* d_ws, size_t ws_size,
                              hipStream_t stream)
{
    (void)in_sizes; (void)n_in; (void)out_size; (void)ws_size;
    const float* x      = (const float*)d_in[0];
    const float* w_qkv  = (const float*)d_in[1];
    const float* w_proj = (const float*)d_in[2];
    const float* b_proj = (const float*)d_in[3];
    float* out = (float*)d_out;

    char* w = (char*)d_ws;
    // workspace layout (bytes):
    u16*   xbf  = (u16*)  (w);                     //  25,165,824  x bf16 [16384][768]
    u16*   wqv  = (u16*)  (w + 25165824);          //   2,359,296  w q+v rows bf16 [1536][768]
    u16*   wpb  = (u16*)  (w + 27525120);          //   1,179,648  w_proj bf16 [768][768]
    float* qbuf = (float*)(w + 28704768);          //  50,331,648  q fp32 [768][256][64]
    u16*   vbfT = (u16*)  (w + 79036416);          //  25,165,824  v^T bf16 [768][64][256]
    u16*   ctxc = (u16*)  (w + 104202240);         //  25,165,824  ctx bf16 [64][256][768]
    float* ub   = (float*)(w + 129368064);         //     786,432  u [768][256]
    float* vb   = (float*)(w + 130154496);         //     786,432  v [768][256]
    float* tmx  = (float*)(w + 130940928);         //       3,072  tmax [768]
    u16*   Km   = (u16*)  (w + 130944000);         // 100,663,296  K bf16 [768][256][256]
    // total ~231.6 MB

    conv_bf16       <<<dim3(6144),    256, 0, stream>>>(x, xbf, 1572864);
    conv_wqv        <<<dim3(576),     256, 0, stream>>>(w_qkv, wqv);
    conv_bf16       <<<dim3(288),     256, 0, stream>>>(w_proj, wpb, 73728);
    gemm_qkv_mfma   <<<dim3(128, 12), 256, 0, stream>>>(xbf, wqv, qbuf, vbfT);
    normalize_kernel<<<dim3(49152),   256, 0, stream>>>(qbuf);
    cost_kernel     <<<dim3(4, 768),  256, 0, stream>>>(qbuf, Km);
    sinkhorn_kernel <<<dim3(768),     512, 0, stream>>>(Km, ub, vb, tmx);
    softpv_kernel   <<<dim3(768),     256, 0, stream>>>(Km, vbfT, ub, vb, tmx, ctxc);
    gemm_proj_mfma  <<<dim3(128, 6),  256, 0, stream>>>(ctxc, wpb, b_proj, out);
}

// Round 5
// 304.100 us; speedup vs baseline: 4.1861x; 1.1612x over previous
//
#include <hip/hip_runtime.h>

typedef unsigned short u16;
typedef unsigned int   u32;
typedef __attribute__((ext_vector_type(8))) short bf16x8;
typedef __attribute__((ext_vector_type(4))) float f32x4;

// ---------- bf16 helpers (manual, RNE) ----------
__device__ __forceinline__ u16 f2bf(float f) {
    u32 u = __float_as_uint(f);
    u += 0x7fffu + ((u >> 16) & 1u);
    return (u16)(u >> 16);
}
__device__ __forceinline__ float bf2f(u16 s) {
    return __uint_as_float(((u32)s) << 16);
}
__device__ __forceinline__ u32 pack2bf(float f0, float f1) {
    return (u32)f2bf(f0) | ((u32)f2bf(f1) << 16);
}

__device__ __forceinline__ void gload_lds16(const void* g, void* l) {
    __builtin_amdgcn_global_load_lds(
        (const __attribute__((address_space(1))) u32*)g,
        (__attribute__((address_space(3))) u32*)l, 16, 0, 0);
}

// =======================================================================
// fp32 -> bf16 converters
// =======================================================================
__global__ __launch_bounds__(256)
void conv_bf16(const float* __restrict__ src, u16* __restrict__ dst, int n8)
{
    const int i = blockIdx.x * 256 + threadIdx.x;   // 8 elements per thread
    if (i < n8) {
        const float4 a = ((const float4*)src)[2*i];
        const float4 b = ((const float4*)src)[2*i + 1];
        ((uint4*)dst)[i] = make_uint4(pack2bf(a.x,a.y), pack2bf(a.z,a.w),
                                      pack2bf(b.x,b.y), pack2bf(b.z,b.w));
    }
}

// w_qkv [2304][768]: keep q rows 0..767 and v rows 1536..2303 -> wqv [1536][768]
__global__ __launch_bounds__(256)
void conv_wqv(const float* __restrict__ w, u16* __restrict__ dst)
{
    const int i = blockIdx.x * 256 + threadIdx.x;   // chunk of 8, 96 chunks/row
    const int row = i / 96;
    const int cc  = (i - row * 96) * 8;
    const int srow = row + (row >= 768 ? 768 : 0);
    const float4 a = *(const float4*)&w[(size_t)srow*768 + cc];
    const float4 b = *(const float4*)&w[(size_t)srow*768 + cc + 4];
    *(uint4*)&dst[(size_t)row*768 + cc] =
        make_uint4(pack2bf(a.x,a.y), pack2bf(a.z,a.w), pack2bf(b.x,b.y), pack2bf(b.z,b.w));
}

// =======================================================================
// Shared MFMA GEMM core: C[128x128] tile, K=768, bf16 A[.,768] x B[.,768]^T.
// BK=64, 4 waves (2x2), 16x16x32 MFMA, global_load_lds + XOR-swizzled LDS.
// =======================================================================
__device__ __forceinline__ void mfma_gemm_core(
    const char* __restrict__ Arow0,   // &A[m0][0] as bytes (row stride 1536)
    const char* __restrict__ Brow0,   // &B[n0][0] as bytes
    u16* As, u16* Bs, const int tid, f32x4 acc[4][4])
{
    const int l  = tid & 63, w = tid >> 6;
    const int wr = w >> 1,  wc = w & 1;
    char* Asb = (char*)As;
    char* Bsb = (char*)Bs;
    const int co = 16 * ((l & 7) ^ (l >> 3));       // swizzled global byte col
    const size_t rstep = (size_t)(l >> 3) * 1536;
    const int rsw = (l & 7) << 4;                   // read-side XOR

    for (int k0 = 0; k0 < 1536; k0 += 128) {        // 12 K-steps of 64 bf16
        #pragma unroll
        for (int i = 0; i < 4; ++i) {
            const int rb = i*32 + w*8;
            gload_lds16(Arow0 + (size_t)rb*1536 + rstep + k0 + co, Asb + i*4096 + w*1024);
            gload_lds16(Brow0 + (size_t)rb*1536 + rstep + k0 + co, Bsb + i*4096 + w*1024);
        }
        __syncthreads();
        bf16x8 af[2][4], bfr[2][4];
        #pragma unroll
        for (int kk = 0; kk < 2; ++kk) {
            const int coff = (kk*64 + ((l >> 4) << 4)) ^ rsw;
            #pragma unroll
            for (int mi = 0; mi < 4; ++mi) {
                const int rowA = wr*64 + mi*16 + (l & 15);
                af[kk][mi]  = *(const bf16x8*)(Asb + rowA*128 + coff);
                const int rowB = wc*64 + mi*16 + (l & 15);
                bfr[kk][mi] = *(const bf16x8*)(Bsb + rowB*128 + coff);
            }
        }
        #pragma unroll
        for (int mi = 0; mi < 4; ++mi)
            #pragma unroll
            for (int nj = 0; nj < 4; ++nj) {
                acc[mi][nj] = __builtin_amdgcn_mfma_f32_16x16x32_bf16(
                                  af[0][mi], bfr[0][nj], acc[mi][nj], 0, 0, 0);
                acc[mi][nj] = __builtin_amdgcn_mfma_f32_16x16x32_bf16(
                                  af[1][mi], bfr[1][nj], acc[mi][nj], 0, 0, 0);
            }
        __syncthreads();
    }
}

// =======================================================================
// K0: q/v projection. xbf [16384][768] bf16, wqv [1536][768] bf16.
// bj<6 -> q cols (fp32 out, [bh][n][64]); bj>=6 -> v cols, written
// TRANSPOSED as vbfT [bh][d=64][m=256] bf16 for softpv's Vt staging.
// =======================================================================
__global__ __launch_bounds__(256)
void gemm_qkv_mfma(const u16* __restrict__ xbf, const u16* __restrict__ wqv,
                   float* __restrict__ qbuf, u16* __restrict__ vbfT)
{
    __shared__ u16 As[128*64];
    __shared__ u16 Bs[128*64];
    const int m0 = blockIdx.x * 128;
    const int bj = blockIdx.y;
    const int tid = threadIdx.x;
    f32x4 acc[4][4];
    #pragma unroll
    for (int i = 0; i < 4; ++i)
        #pragma unroll
        for (int j = 0; j < 4; ++j) acc[i][j] = (f32x4){0.f,0.f,0.f,0.f};

    mfma_gemm_core((const char*)xbf + (size_t)m0*1536,
                   (const char*)wqv + (size_t)bj*128*1536,
                   As, Bs, tid, acc);

    const int l = tid & 63, w = tid >> 6;
    const int wr = w >> 1, wc = w & 1;
    const int colb = (bj % 6)*128 + wc*64;
    const int rbase = m0 + wr*64 + ((l >> 4) << 2);
    if (bj < 6) {
        #pragma unroll
        for (int mi = 0; mi < 4; ++mi)
            #pragma unroll
            for (int nj = 0; nj < 4; ++nj) {
                const int col = colb + nj*16 + (l & 15);
                const int h = col >> 6, d = col & 63;
                #pragma unroll
                for (int rr = 0; rr < 4; ++rr) {
                    const int m = rbase + mi*16 + rr;
                    const int b_ = m >> 8, n_ = m & 255;
                    qbuf[((((size_t)b_*12 + h) << 8) + n_)*64 + d] = acc[mi][nj][rr];
                }
            }
    } else {
        #pragma unroll
        for (int mi = 0; mi < 4; ++mi)
            #pragma unroll
            for (int nj = 0; nj < 4; ++nj) {
                const int col = colb + nj*16 + (l & 15);
                const int h = col >> 6, d = col & 63;
                const int m = rbase + mi*16;        // rows m..m+3 (consecutive)
                const int b_ = m >> 8, n_ = m & 255;
                uint2 o = make_uint2(pack2bf(acc[mi][nj][0], acc[mi][nj][1]),
                                     pack2bf(acc[mi][nj][2], acc[mi][nj][3]));
                *(uint2*)&vbfT[(((size_t)b_*12 + h)*64 + d)*256 + n_] = o;
            }
    }
}

// =======================================================================
// K5: out = ctx @ w_proj^T + b_proj. ctxb [16384][768] bf16, wpb [768][768] bf16.
// =======================================================================
__global__ __launch_bounds__(256)
void gemm_proj_mfma(const u16* __restrict__ ctxb, const u16* __restrict__ wpb,
                    const float* __restrict__ bias, float* __restrict__ out)
{
    __shared__ u16 As[128*64];
    __shared__ u16 Bs[128*64];
    const int m0 = blockIdx.x * 128;
    const int n0 = blockIdx.y * 128;
    const int tid = threadIdx.x;
    f32x4 acc[4][4];
    #pragma unroll
    for (int i = 0; i < 4; ++i)
        #pragma unroll
        for (int j = 0; j < 4; ++j) acc[i][j] = (f32x4){0.f,0.f,0.f,0.f};

    mfma_gemm_core((const char*)ctxb + (size_t)m0*1536,
                   (const char*)wpb + (size_t)n0*1536,
                   As, Bs, tid, acc);

    const int l = tid & 63, w = tid >> 6;
    const int wr = w >> 1, wc = w & 1;
    const int rbase = m0 + wr*64 + ((l >> 4) << 2);
    #pragma unroll
    for (int mi = 0; mi < 4; ++mi)
        #pragma unroll
        for (int nj = 0; nj < 4; ++nj) {
            const int col = n0 + wc*64 + nj*16 + (l & 15);
            const float bv = bias[col];
            #pragma unroll
            for (int rr = 0; rr < 4; ++rr) {
                const int m = rbase + mi*16 + rr;
                out[(size_t)m*768 + col] = acc[mi][nj][rr] + bv;
            }
        }
}

// =======================================================================
// K1: normalize q rows in place: q /= (||q|| + 1e-8). One wave per row.
// =======================================================================
__global__ __launch_bounds__(256)
void normalize_kernel(float* __restrict__ q)
{
    const int row = blockIdx.x * 4 + (threadIdx.x >> 6);
    const int d   = threadIdx.x & 63;
    const size_t idx = (size_t)row * 64 + d;
    const float val = q[idx];
    float s = val * val;
    #pragma unroll
    for (int off = 32; off > 0; off >>= 1) s += __shfl_xor(s, off);
    q[idx] = val / (sqrtf(s) + 1e-8f);
}

// =======================================================================
// K2: K[n][m] = exp(10*cos(n,m) - 10) off-diag, 0 on diag. bf16 out.
// =======================================================================
__global__ __launch_bounds__(256)
void cost_kernel(const float* __restrict__ qn, u16* __restrict__ Kmat)
{
    __shared__ float Qak[64][128];
    __shared__ float Qbk[64][128];
    const int bh = blockIdx.y;
    const int tr = (blockIdx.x >> 1) * 128;
    const int tc = (blockIdx.x & 1) * 128;
    const float* qb = qn + (size_t)bh * (256 * 64);
    const int tid = threadIdx.x;
    const int tx = tid & 15, ty = tid >> 4;
    {
        const int r  = tid >> 1;            // 0..127
        const int kb = (tid & 1) * 32;
        #pragma unroll
        for (int qq = 0; qq < 8; ++qq) {
            const int k = kb + qq * 4;
            float4 a = *(const float4*)&qb[(size_t)(tr + r) * 64 + k];
            Qak[k+0][r] = a.x; Qak[k+1][r] = a.y; Qak[k+2][r] = a.z; Qak[k+3][r] = a.w;
            float4 b = *(const float4*)&qb[(size_t)(tc + r) * 64 + k];
            Qbk[k+0][r] = b.x; Qbk[k+1][r] = b.y; Qbk[k+2][r] = b.z; Qbk[k+3][r] = b.w;
        }
    }
    __syncthreads();
    float acc[8][8];
    #pragma unroll
    for (int i = 0; i < 8; ++i)
        #pragma unroll
        for (int j = 0; j < 8; ++j) acc[i][j] = 0.f;
    #pragma unroll 4
    for (int k = 0; k < 64; ++k) {
        float4 a0 = *(const float4*)&Qak[k][4*ty];
        float4 a1 = *(const float4*)&Qak[k][64 + 4*ty];
        float4 b0 = *(const float4*)&Qbk[k][4*tx];
        float4 b1 = *(const float4*)&Qbk[k][64 + 4*tx];
        float a[8] = {a0.x,a0.y,a0.z,a0.w,a1.x,a1.y,a1.z,a1.w};
        float b[8] = {b0.x,b0.y,b0.z,b0.w,b1.x,b1.y,b1.z,b1.w};
        #pragma unroll
        for (int i = 0; i < 8; ++i)
            #pragma unroll
            for (int j = 0; j < 8; ++j)
                acc[i][j] = fmaf(a[i], b[j], acc[i][j]);
    }
    u16* Kb = Kmat + (size_t)bh * 65536;
    #pragma unroll
    for (int rp = 0; rp < 2; ++rp)
        #pragma unroll
        for (int i = 0; i < 4; ++i) {
            const int gr = tr + rp*64 + 4*ty + i;
            #pragma unroll
            for (int cp = 0; cp < 2; ++cp) {
                const int gc0 = tc + cp*64 + 4*tx;
                float km[4];
                #pragma unroll
                for (int j = 0; j < 4; ++j) {
                    const float s = acc[rp*4+i][cp*4+j];
                    km[j] = (gr == gc0 + j) ? 0.f : __expf(fmaf(10.f, s, -10.f));
                }
                *(uint2*)&Kb[(size_t)gr * 256 + gc0] =
                    make_uint2(pack2bf(km[0], km[1]), pack2bf(km[2], km[3]));
            }
        }
}

// =======================================================================
// K3 (rewritten): Sinkhorn with K held in MFMA A-frags (VGPRs), matvec on
// matrix cores. One block of 512 thr per (b,h); wave w owns rows 32w..32w+31
// as 16 bf16x8 frags (64 VGPR), loaded from global ONCE. Per iteration:
// y = K x via 16 chained mfma (B = x broadcast into all 16 cols, bf16 LDS);
// x' = (1/256)/y. Internal k-permutation cancels between A and B slots since
// B depends only on k. D-layout row=(l>>4)*4+reg col=l&15 (HW-verified).
// LDS ~4KB, VGPR<=128 -> 2 blocks/CU.
// =======================================================================
__global__ __launch_bounds__(512, 4)
void sinkhorn_kernel(const u16* __restrict__ Kmat, float* __restrict__ ubuf,
                     float* __restrict__ vbuf, float* __restrict__ tmaxbuf)
{
    __shared__ __align__(16) float ys[256];
    __shared__ __align__(16) float xv[256];
    __shared__ __align__(16) float usave[256];
    __shared__ __align__(16) u16   xbf[256];
    __shared__ float pmax[8];
    const int bh  = blockIdx.x;
    const int tid = threadIdx.x;
    const int l = tid & 63, w = tid >> 6;
    const int rowb = w * 32;
    const char* Kg = (const char*)(Kmat + (size_t)bh * 65536);

    // ---- K frags: lane l holds K[rowb + t*16 + (l&15)][ks*32 + (l>>4)*8 + j]
    bf16x8 kf[2][8];
    {
        const char* kb0 = Kg + (size_t)(rowb + (l & 15)) * 512 + ((l >> 4) << 4);
        #pragma unroll
        for (int t = 0; t < 2; ++t)
            #pragma unroll
            for (int ks = 0; ks < 8; ++ks)
                kf[t][ks] = *(const bf16x8*)(kb0 + t*8192 + ks*64);
    }
    if (tid < 256) { xv[tid] = 1.0f; xbf[tid] = 0x3f80; }   // bf16(1.0)
    __syncthreads();

    for (int it = 0; it < 20; ++it) {
        f32x4 a0 = {0.f,0.f,0.f,0.f}, a1 = {0.f,0.f,0.f,0.f};
        #pragma unroll
        for (int ks = 0; ks < 8; ++ks) {
            const bf16x8 xf = *(const bf16x8*)((const char*)xbf + ks*64 + ((l >> 4) << 4));
            a0 = __builtin_amdgcn_mfma_f32_16x16x32_bf16(kf[0][ks], xf, a0, 0, 0, 0);
            a1 = __builtin_amdgcn_mfma_f32_16x16x32_bf16(kf[1][ks], xf, a1, 0, 0, 0);
        }
        if ((l & 15) == 0) {                 // 4 lanes publish 2x4 rows each
            const int r0 = rowb + ((l >> 4) << 2);
            *(float4*)&ys[r0]      = make_float4(a0[0], a0[1], a0[2], a0[3]);
            *(float4*)&ys[r0 + 16] = make_float4(a1[0], a1[1], a1[2], a1[3]);
        }
        __syncthreads();
        if (tid < 256) {
            const float xn = 0.00390625f / ys[tid];   // (1/256)/y
            if (it == 18) usave[tid] = xn;            // u after 19th half-step
            xv[tid]  = xn;
            xbf[tid] = f2bf(xn);
        }
        __syncthreads();
    }

    // ---- Tmax = max u[n] K[n][m] v[m]; frags cover all (row,k) pairs once
    float mx = 0.f;
    {
        const float u0 = usave[rowb + (l & 15)];
        const float u1 = usave[rowb + 16 + (l & 15)];
        #pragma unroll
        for (int ks = 0; ks < 8; ++ks) {
            const float4 va = *(const float4*)&xv[ks*32 + ((l >> 4) << 3)];
            const float4 vb4 = *(const float4*)&xv[ks*32 + ((l >> 4) << 3) + 4];
            const float vv[8] = {va.x, va.y, va.z, va.w, vb4.x, vb4.y, vb4.z, vb4.w};
            #pragma unroll
            for (int j = 0; j < 8; ++j) {
                mx = fmaxf(mx, u0 * bf2f((u16)kf[0][ks][j]) * vv[j]);
                mx = fmaxf(mx, u1 * bf2f((u16)kf[1][ks][j]) * vv[j]);
            }
        }
    }
    #pragma unroll
    for (int off = 32; off > 0; off >>= 1) mx = fmaxf(mx, __shfl_xor(mx, off));
    if (l == 0) pmax[w] = mx;
    __syncthreads();
    if (tid < 256) {
        ubuf[bh * 256 + tid] = usave[tid];
        vbuf[bh * 256 + tid] = xv[tid];
    }
    if (tid == 0) {
        float m = pmax[0];
        #pragma unroll
        for (int i = 1; i < 8; ++i) m = fmaxf(m, pmax[i]);
        tmaxbuf[bh] = m;
    }
}

// =======================================================================
// K4: per (b,h), 256 threads / 4 waves; thread-per-row P + MFMA PV.
// =======================================================================
__global__ __launch_bounds__(256)
void softpv_kernel(const u16* __restrict__ Kmat, const u16* __restrict__ vbfT,
                   const float* __restrict__ ubuf, const float* __restrict__ vbuf,
                   const float* __restrict__ tmaxbuf, u16* __restrict__ ctxc)
{
    __shared__ u16 Vt[64*256];     // [d][m] bf16, swizzled: slot s holds global slot s^(d&7)
    __shared__ u16 Pl[256*64];     // [n][m-chunk] bf16, swizzled: slot i at i^(n&7)
    __shared__ float vmf[256];
    __shared__ float sinv[256];
    const int bh = blockIdx.x;
    const int b_ = bh / 12, h_ = bh - b_*12;
    const int tid = threadIdx.x;
    const int l = tid & 63, w = tid >> 6;

    // ---- stage Vt (32 KB): 8 issues x (256 thr x 16B); source pre-swizzled
    {
        const char* src = (const char*)(vbfT + (size_t)bh * 16384);
        char* dst = (char*)Vt;
        const int s = l & 31;                      // 16B slot within 512B row
        #pragma unroll
        for (int i = 0; i < 8; ++i) {
            const int d = i*8 + w*2 + (l >> 5);
            gload_lds16(src + d*512 + ((s ^ (d & 7)) << 4), dst + i*4096 + w*1024);
        }
    }
    vmf[tid] = vbuf[bh*256 + tid];
    const float an = ubuf[bh*256 + tid] * (1.0f / tmaxbuf[bh]) * 0.125f;
    const u16* Krow = Kmat + (size_t)bh*65536 + (size_t)tid*256;
    __syncthreads();                               // Vt + vmf resident

    f32x4 acc[4][4];                               // [mi=d-frag][nj=n-frag]
    #pragma unroll
    for (int i = 0; i < 4; ++i)
        #pragma unroll
        for (int j = 0; j < 4; ++j) acc[i][j] = (f32x4){0.f,0.f,0.f,0.f};
    float psum = 0.f;
    char* prow = (char*)Pl + tid*128;
    const int nsw = tid & 7;

    #pragma unroll
    for (int mc = 0; mc < 4; ++mc) {
        // ---- P row chunk: 8 x uint4 K loads, exp, pack, swizzled ds_write
        const uint4* kr = (const uint4*)(Krow + mc*64);
        #pragma unroll
        for (int i = 0; i < 8; ++i) {
            const uint4 raw = kr[i];
            const float4 va = *(const float4*)&vmf[mc*64 + i*8];
            const float4 vbq = *(const float4*)&vmf[mc*64 + i*8 + 4];
            float p[8];
            p[0] = __expf(an * bf2f((u16)(raw.x & 0xffffu)) * va.x);
            p[1] = __expf(an * bf2f((u16)(raw.x >> 16))     * va.y);
            p[2] = __expf(an * bf2f((u16)(raw.y & 0xffffu)) * va.z);
            p[3] = __expf(an * bf2f((u16)(raw.y >> 16))     * va.w);
            p[4] = __expf(an * bf2f((u16)(raw.z & 0xffffu)) * vbq.x);
            p[5] = __expf(an * bf2f((u16)(raw.z >> 16))     * vbq.y);
            p[6] = __expf(an * bf2f((u16)(raw.w & 0xffffu)) * vbq.z);
            p[7] = __expf(an * bf2f((u16)(raw.w >> 16))     * vbq.w);
            const int dj = tid - mc*64 - i*8;      // diagonal override
            if (dj >= 0 && dj < 8) p[dj] = 1.13314845f;   // exp(0.125)
            psum += ((p[0]+p[1]) + (p[2]+p[3])) + ((p[4]+p[5]) + (p[6]+p[7]));
            uint4 pw = make_uint4(pack2bf(p[0],p[1]), pack2bf(p[2],p[3]),
                                  pack2bf(p[4],p[5]), pack2bf(p[6],p[7]));
            *(uint4*)(prow + ((i ^ nsw) << 4)) = pw;
        }
        // ---- MFMA: D[d][n] += Vt[d][m-chunk] * P[n][m-chunk]
        #pragma unroll
        for (int kk = 0; kk < 2; ++kk) {
            bf16x8 afr[4], bfr[4];
            const int kb = kk*64 + ((l >> 4) << 4);
            #pragma unroll
            for (int f = 0; f < 4; ++f) {
                const int d = f*16 + (l & 15);
                afr[f] = *(const bf16x8*)((char*)Vt + d*512 + ((mc*128 + kb) ^ ((d & 7) << 4)));
                const int n = w*64 + f*16 + (l & 15);
                bfr[f] = *(const bf16x8*)((char*)Pl + n*128 + (kb ^ ((n & 7) << 4)));
            }
            #pragma unroll
            for (int mi = 0; mi < 4; ++mi)
                #pragma unroll
                for (int nj = 0; nj < 4; ++nj)
                    acc[mi][nj] = __builtin_amdgcn_mfma_f32_16x16x32_bf16(
                                      afr[mi], bfr[nj], acc[mi][nj], 0, 0, 0);
        }
    }
    sinv[tid] = 1.0f / psum;
    __syncthreads();
    // ---- epilogue: lane col = n, regs rr -> d consecutive
    u16* outp = ctxc + ((size_t)b_*256)*768 + h_*64;
    #pragma unroll
    for (int nj = 0; nj < 4; ++nj) {
        const int n = w*64 + nj*16 + (l & 15);
        const float is = sinv[n];
        #pragma unroll
        for (int mi = 0; mi < 4; ++mi) {
            const int d0 = mi*16 + ((l >> 4) << 2);
            uint2 o = make_uint2(pack2bf(acc[mi][nj][0]*is, acc[mi][nj][1]*is),
                                 pack2bf(acc[mi][nj][2]*is, acc[mi][nj][3]*is));
            *(uint2*)&outp[(size_t)n*768 + d0] = o;
        }
    }
}

// =======================================================================
extern "C" void kernel_launch(void* const* d_in, const int* in_sizes, int n_in,
                              void* d_out, int out_size, void* d_ws, size_t ws_size,
                              hipStream_t stream)
{
    (void)in_sizes; (void)n_in; (void)out_size; (void)ws_size;
    const float* x      = (const float*)d_in[0];
    const float* w_qkv  = (const float*)d_in[1];
    const float* w_proj = (const float*)d_in[2];
    const float* b_proj = (const float*)d_in[3];
    float* out = (float*)d_out;

    char* w = (char*)d_ws;
    // workspace layout (bytes):
    u16*   xbf  = (u16*)  (w);                     //  25,165,824  x bf16 [16384][768]
    u16*   wqv  = (u16*)  (w + 25165824);          //   2,359,296  w q+v rows bf16 [1536][768]
    u16*   wpb  = (u16*)  (w + 27525120);          //   1,179,648  w_proj bf16 [768][768]
    float* qbuf = (float*)(w + 28704768);          //  50,331,648  q fp32 [768][256][64]
    u16*   vbfT = (u16*)  (w + 79036416);          //  25,165,824  v^T bf16 [768][64][256]
    u16*   ctxc = (u16*)  (w + 104202240);         //  25,165,824  ctx bf16 [64][256][768]
    float* ub   = (float*)(w + 129368064);         //     786,432  u [768][256]
    float* vb   = (float*)(w + 130154496);         //     786,432  v [768][256]
    float* tmx  = (float*)(w + 130940928);         //       3,072  tmax [768]
    u16*   Km   = (u16*)  (w + 130944000);         // 100,663,296  K bf16 [768][256][256]
    // total ~231.6 MB

    conv_bf16       <<<dim3(6144),    256, 0, stream>>>(x, xbf, 1572864);
    conv_wqv        <<<dim3(576),     256, 0, stream>>>(w_qkv, wqv);
    conv_bf16       <<<dim3(288),     256, 0, stream>>>(w_proj, wpb, 73728);
    gemm_qkv_mfma   <<<dim3(128, 12), 256, 0, stream>>>(xbf, wqv, qbuf, vbfT);
    normalize_kernel<<<dim3(49152),   256, 0, stream>>>(qbuf);
    cost_kernel     <<<dim3(4, 768),  256, 0, stream>>>(qbuf, Km);
    sinkhorn_kernel <<<dim3(768),     512, 0, stream>>>(Km, ub, vb, tmx);
    softpv_kernel   <<<dim3(768),     256, 0, stream>>>(Km, vbfT, ub, vb, tmx, ctxc);
    gemm_proj_mfma  <<<dim3(128, 6),  256, 0, stream>>>(ctxc, wpb, b_proj, out);
}

// Round 6
// 247.656 us; speedup vs baseline: 5.1402x; 1.2279x over previous
//
#include <hip/hip_runtime.h>

typedef unsigned short u16;
typedef unsigned int   u32;
typedef __attribute__((ext_vector_type(8))) short bf16x8;
typedef __attribute__((ext_vector_type(4))) float f32x4;

// ---------- bf16 helpers (manual, RNE) ----------
__device__ __forceinline__ u16 f2bf(float f) {
    u32 u = __float_as_uint(f);
    u += 0x7fffu + ((u >> 16) & 1u);
    return (u16)(u >> 16);
}
__device__ __forceinline__ float bf2f(u16 s) {
    return __uint_as_float(((u32)s) << 16);
}
__device__ __forceinline__ u32 pack2bf(float f0, float f1) {
    return (u32)f2bf(f0) | ((u32)f2bf(f1) << 16);
}

__device__ __forceinline__ void gload_lds16(const void* g, void* l) {
    __builtin_amdgcn_global_load_lds(
        (const __attribute__((address_space(1))) u32*)g,
        (__attribute__((address_space(3))) u32*)l, 16, 0, 0);
}

// =======================================================================
// fp32 -> bf16 converters
// =======================================================================
__global__ __launch_bounds__(256)
void conv_bf16(const float* __restrict__ src, u16* __restrict__ dst, int n8)
{
    const int i = blockIdx.x * 256 + threadIdx.x;   // 8 elements per thread
    if (i < n8) {
        const float4 a = ((const float4*)src)[2*i];
        const float4 b = ((const float4*)src)[2*i + 1];
        ((uint4*)dst)[i] = make_uint4(pack2bf(a.x,a.y), pack2bf(a.z,a.w),
                                      pack2bf(b.x,b.y), pack2bf(b.z,b.w));
    }
}

// w_qkv [2304][768]: keep q rows 0..767 and v rows 1536..2303 -> wqv [1536][768]
__global__ __launch_bounds__(256)
void conv_wqv(const float* __restrict__ w, u16* __restrict__ dst)
{
    const int i = blockIdx.x * 256 + threadIdx.x;   // chunk of 8, 96 chunks/row
    const int row = i / 96;
    const int cc  = (i - row * 96) * 8;
    const int srow = row + (row >= 768 ? 768 : 0);
    const float4 a = *(const float4*)&w[(size_t)srow*768 + cc];
    const float4 b = *(const float4*)&w[(size_t)srow*768 + cc + 4];
    *(uint4*)&dst[(size_t)row*768 + cc] =
        make_uint4(pack2bf(a.x,a.y), pack2bf(a.z,a.w), pack2bf(b.x,b.y), pack2bf(b.z,b.w));
}

// =======================================================================
// Shared MFMA GEMM core: C[128x128] tile, K=768, bf16 A[.,768] x B[.,768]^T.
// BK=64, 4 waves (2x2), 16x16x32 MFMA, global_load_lds + XOR-swizzled LDS.
// =======================================================================
__device__ __forceinline__ void mfma_gemm_core(
    const char* __restrict__ Arow0,   // &A[m0][0] as bytes (row stride 1536)
    const char* __restrict__ Brow0,   // &B[n0][0] as bytes
    u16* As, u16* Bs, const int tid, f32x4 acc[4][4])
{
    const int l  = tid & 63, w = tid >> 6;
    const int wr = w >> 1,  wc = w & 1;
    char* Asb = (char*)As;
    char* Bsb = (char*)Bs;
    const int co = 16 * ((l & 7) ^ (l >> 3));       // swizzled global byte col
    const size_t rstep = (size_t)(l >> 3) * 1536;
    const int rsw = (l & 7) << 4;                   // read-side XOR

    for (int k0 = 0; k0 < 1536; k0 += 128) {        // 12 K-steps of 64 bf16
        #pragma unroll
        for (int i = 0; i < 4; ++i) {
            const int rb = i*32 + w*8;
            gload_lds16(Arow0 + (size_t)rb*1536 + rstep + k0 + co, Asb + i*4096 + w*1024);
            gload_lds16(Brow0 + (size_t)rb*1536 + rstep + k0 + co, Bsb + i*4096 + w*1024);
        }
        __syncthreads();
        bf16x8 af[2][4], bfr[2][4];
        #pragma unroll
        for (int kk = 0; kk < 2; ++kk) {
            const int coff = (kk*64 + ((l >> 4) << 4)) ^ rsw;
            #pragma unroll
            for (int mi = 0; mi < 4; ++mi) {
                const int rowA = wr*64 + mi*16 + (l & 15);
                af[kk][mi]  = *(const bf16x8*)(Asb + rowA*128 + coff);
                const int rowB = wc*64 + mi*16 + (l & 15);
                bfr[kk][mi] = *(const bf16x8*)(Bsb + rowB*128 + coff);
            }
        }
        #pragma unroll
        for (int mi = 0; mi < 4; ++mi)
            #pragma unroll
            for (int nj = 0; nj < 4; ++nj) {
                acc[mi][nj] = __builtin_amdgcn_mfma_f32_16x16x32_bf16(
                                  af[0][mi], bfr[0][nj], acc[mi][nj], 0, 0, 0);
                acc[mi][nj] = __builtin_amdgcn_mfma_f32_16x16x32_bf16(
                                  af[1][mi], bfr[1][nj], acc[mi][nj], 0, 0, 0);
            }
        __syncthreads();
    }
}

// =======================================================================
// K0: q/v projection. xbf [16384][768] bf16, wqv [1536][768] bf16.
// bj<6 -> q cols (fp32 out, [bh][n][64]); bj>=6 -> v cols, written
// TRANSPOSED as vbfT [bh][d=64][m=256] bf16 for softpv's Vt staging.
// =======================================================================
__global__ __launch_bounds__(256)
void gemm_qkv_mfma(const u16* __restrict__ xbf, const u16* __restrict__ wqv,
                   float* __restrict__ qbuf, u16* __restrict__ vbfT)
{
    __shared__ u16 As[128*64];
    __shared__ u16 Bs[128*64];
    const int m0 = blockIdx.x * 128;
    const int bj = blockIdx.y;
    const int tid = threadIdx.x;
    f32x4 acc[4][4];
    #pragma unroll
    for (int i = 0; i < 4; ++i)
        #pragma unroll
        for (int j = 0; j < 4; ++j) acc[i][j] = (f32x4){0.f,0.f,0.f,0.f};

    mfma_gemm_core((const char*)xbf + (size_t)m0*1536,
                   (const char*)wqv + (size_t)bj*128*1536,
                   As, Bs, tid, acc);

    const int l = tid & 63, w = tid >> 6;
    const int wr = w >> 1, wc = w & 1;
    const int colb = (bj % 6)*128 + wc*64;
    const int rbase = m0 + wr*64 + ((l >> 4) << 2);
    if (bj < 6) {
        #pragma unroll
        for (int mi = 0; mi < 4; ++mi)
            #pragma unroll
            for (int nj = 0; nj < 4; ++nj) {
                const int col = colb + nj*16 + (l & 15);
                const int h = col >> 6, d = col & 63;
                #pragma unroll
                for (int rr = 0; rr < 4; ++rr) {
                    const int m = rbase + mi*16 + rr;
                    const int b_ = m >> 8, n_ = m & 255;
                    qbuf[((((size_t)b_*12 + h) << 8) + n_)*64 + d] = acc[mi][nj][rr];
                }
            }
    } else {
        #pragma unroll
        for (int mi = 0; mi < 4; ++mi)
            #pragma unroll
            for (int nj = 0; nj < 4; ++nj) {
                const int col = colb + nj*16 + (l & 15);
                const int h = col >> 6, d = col & 63;
                const int m = rbase + mi*16;        // rows m..m+3 (consecutive)
                const int b_ = m >> 8, n_ = m & 255;
                uint2 o = make_uint2(pack2bf(acc[mi][nj][0], acc[mi][nj][1]),
                                     pack2bf(acc[mi][nj][2], acc[mi][nj][3]));
                *(uint2*)&vbfT[(((size_t)b_*12 + h)*64 + d)*256 + n_] = o;
            }
    }
}

// =======================================================================
// K5: out = ctx @ w_proj^T + b_proj. ctxb [16384][768] bf16, wpb [768][768] bf16.
// =======================================================================
__global__ __launch_bounds__(256)
void gemm_proj_mfma(const u16* __restrict__ ctxb, const u16* __restrict__ wpb,
                    const float* __restrict__ bias, float* __restrict__ out)
{
    __shared__ u16 As[128*64];
    __shared__ u16 Bs[128*64];
    const int m0 = blockIdx.x * 128;
    const int n0 = blockIdx.y * 128;
    const int tid = threadIdx.x;
    f32x4 acc[4][4];
    #pragma unroll
    for (int i = 0; i < 4; ++i)
        #pragma unroll
        for (int j = 0; j < 4; ++j) acc[i][j] = (f32x4){0.f,0.f,0.f,0.f};

    mfma_gemm_core((const char*)ctxb + (size_t)m0*1536,
                   (const char*)wpb + (size_t)n0*1536,
                   As, Bs, tid, acc);

    const int l = tid & 63, w = tid >> 6;
    const int wr = w >> 1, wc = w & 1;
    const int rbase = m0 + wr*64 + ((l >> 4) << 2);
    #pragma unroll
    for (int mi = 0; mi < 4; ++mi)
        #pragma unroll
        for (int nj = 0; nj < 4; ++nj) {
            const int col = n0 + wc*64 + nj*16 + (l & 15);
            const float bv = bias[col];
            #pragma unroll
            for (int rr = 0; rr < 4; ++rr) {
                const int m = rbase + mi*16 + rr;
                out[(size_t)m*768 + col] = acc[mi][nj][rr] + bv;
            }
        }
}

// =======================================================================
// K1: normalize q rows: qn = q/(||q||+1e-8), emitted as bf16 [bh][n][64].
// One wave per row.
// =======================================================================
__global__ __launch_bounds__(256)
void normalize_kernel(const float* __restrict__ q, u16* __restrict__ qn)
{
    const int row = blockIdx.x * 4 + (threadIdx.x >> 6);
    const int d   = threadIdx.x & 63;
    const size_t idx = (size_t)row * 64 + d;
    const float val = q[idx];
    float s = val * val;
    #pragma unroll
    for (int off = 32; off > 0; off >>= 1) s += __shfl_xor(s, off);
    qn[idx] = f2bf(val / (sqrtf(s) + 1e-8f));
}

// =======================================================================
// K2 (rewritten): K[n][m] = exp(10*cos(n,m) - 10) off-diag, 0 on diag.
// MFMA 16x16x32 bf16 on qn tiles. Per block: 128x128 output tile of one
// (b,h); 4 waves 2x2; Qa/Qb 16 KB each in LDS, XOR-swizzled (pre-swizzled
// global source, linear gload_lds dest, swizzle-on-read; 2-way bank
// aliasing on ds_read_b128 = free). Fused exp + bf16 pack epilogue.
// =======================================================================
__global__ __launch_bounds__(256)
void cost_kernel(const u16* __restrict__ qnbf, u16* __restrict__ Kmat)
{
    __shared__ u16 Qa[128*64];     // [row][64 k] bf16, slot s holds global slot s^(row&7)
    __shared__ u16 Qb[128*64];
    const int bh = blockIdx.y;
    const int tr = (blockIdx.x >> 1) * 128;
    const int tc = (blockIdx.x & 1) * 128;
    const char* qb = (const char*)(qnbf + (size_t)bh * 16384);
    const int tid = threadIdx.x;
    const int l = tid & 63, w = tid >> 6;
    const int wr = w >> 1, wc = w & 1;

    // ---- stage both tiles: 4 issues/wave/array; rows 8*(i*4+w)+(l>>3)
    {
        const int co = ((l & 7) ^ (l >> 3)) << 4;   // inverse-swizzled source slot
        const int rl = l >> 3;
        #pragma unroll
        for (int i = 0; i < 4; ++i) {
            const int ch = i*4 + w;                 // chunk 0..15
            gload_lds16(qb + (size_t)(tr + ch*8 + rl)*128 + co, (char*)Qa + ch*1024);
            gload_lds16(qb + (size_t)(tc + ch*8 + rl)*128 + co, (char*)Qb + ch*1024);
        }
    }
    __syncthreads();

    f32x4 acc[4][4];
    #pragma unroll
    for (int i = 0; i < 4; ++i)
        #pragma unroll
        for (int j = 0; j < 4; ++j) acc[i][j] = (f32x4){0.f,0.f,0.f,0.f};

    bf16x8 af[2][4], bfr[2][4];
    #pragma unroll
    for (int kk = 0; kk < 2; ++kk) {
        const int kb = kk*64 + ((l >> 4) << 4);
        #pragma unroll
        for (int f = 0; f < 4; ++f) {
            const int ra = wr*64 + f*16 + (l & 15);
            af[kk][f]  = *(const bf16x8*)((char*)Qa + ra*128 + (kb ^ ((ra & 7) << 4)));
            const int rb = wc*64 + f*16 + (l & 15);
            bfr[kk][f] = *(const bf16x8*)((char*)Qb + rb*128 + (kb ^ ((rb & 7) << 4)));
        }
    }
    #pragma unroll
    for (int mi = 0; mi < 4; ++mi)
        #pragma unroll
        for (int nj = 0; nj < 4; ++nj) {
            acc[mi][nj] = __builtin_amdgcn_mfma_f32_16x16x32_bf16(
                              af[0][mi], bfr[0][nj], acc[mi][nj], 0, 0, 0);
            acc[mi][nj] = __builtin_amdgcn_mfma_f32_16x16x32_bf16(
                              af[1][mi], bfr[1][nj], acc[mi][nj], 0, 0, 0);
        }

    // ---- epilogue: exp(10*s - 10), diag -> 0, bf16 store
    u16* Kb = Kmat + (size_t)bh * 65536;
    #pragma unroll
    for (int mi = 0; mi < 4; ++mi)
        #pragma unroll
        for (int nj = 0; nj < 4; ++nj) {
            const int gr0 = tr + wr*64 + mi*16 + ((l >> 4) << 2);
            const int gc  = tc + wc*64 + nj*16 + (l & 15);
            #pragma unroll
            for (int rr = 0; rr < 4; ++rr) {
                const int gr = gr0 + rr;
                const float s = acc[mi][nj][rr];
                const float km = (gr == gc) ? 0.f : __expf(fmaf(10.f, s, -10.f));
                Kb[(size_t)gr * 256 + gc] = f2bf(km);
            }
        }
}

// =======================================================================
// K3: Sinkhorn with K held in MFMA A-frags (VGPRs), matvec on matrix cores.
// =======================================================================
__global__ __launch_bounds__(512, 4)
void sinkhorn_kernel(const u16* __restrict__ Kmat, float* __restrict__ ubuf,
                     float* __restrict__ vbuf, float* __restrict__ tmaxbuf)
{
    __shared__ __align__(16) float ys[256];
    __shared__ __align__(16) float xv[256];
    __shared__ __align__(16) float usave[256];
    __shared__ __align__(16) u16   xbf[256];
    __shared__ float pmax[8];
    const int bh  = blockIdx.x;
    const int tid = threadIdx.x;
    const int l = tid & 63, w = tid >> 6;
    const int rowb = w * 32;
    const char* Kg = (const char*)(Kmat + (size_t)bh * 65536);

    // ---- K frags: lane l holds K[rowb + t*16 + (l&15)][ks*32 + (l>>4)*8 + j]
    bf16x8 kf[2][8];
    {
        const char* kb0 = Kg + (size_t)(rowb + (l & 15)) * 512 + ((l >> 4) << 4);
        #pragma unroll
        for (int t = 0; t < 2; ++t)
            #pragma unroll
            for (int ks = 0; ks < 8; ++ks)
                kf[t][ks] = *(const bf16x8*)(kb0 + t*8192 + ks*64);
    }
    if (tid < 256) { xv[tid] = 1.0f; xbf[tid] = 0x3f80; }   // bf16(1.0)
    __syncthreads();

    for (int it = 0; it < 20; ++it) {
        f32x4 a0 = {0.f,0.f,0.f,0.f}, a1 = {0.f,0.f,0.f,0.f};
        #pragma unroll
        for (int ks = 0; ks < 8; ++ks) {
            const bf16x8 xf = *(const bf16x8*)((const char*)xbf + ks*64 + ((l >> 4) << 4));
            a0 = __builtin_amdgcn_mfma_f32_16x16x32_bf16(kf[0][ks], xf, a0, 0, 0, 0);
            a1 = __builtin_amdgcn_mfma_f32_16x16x32_bf16(kf[1][ks], xf, a1, 0, 0, 0);
        }
        if ((l & 15) == 0) {                 // 4 lanes publish 2x4 rows each
            const int r0 = rowb + ((l >> 4) << 2);
            *(float4*)&ys[r0]      = make_float4(a0[0], a0[1], a0[2], a0[3]);
            *(float4*)&ys[r0 + 16] = make_float4(a1[0], a1[1], a1[2], a1[3]);
        }
        __syncthreads();
        if (tid < 256) {
            const float xn = 0.00390625f / ys[tid];   // (1/256)/y
            if (it == 18) usave[tid] = xn;            // u after 19th half-step
            xv[tid]  = xn;
            xbf[tid] = f2bf(xn);
        }
        __syncthreads();
    }

    // ---- Tmax = max u[n] K[n][m] v[m]; frags cover all (row,k) pairs once
    float mx = 0.f;
    {
        const float u0 = usave[rowb + (l & 15)];
        const float u1 = usave[rowb + 16 + (l & 15)];
        #pragma unroll
        for (int ks = 0; ks < 8; ++ks) {
            const float4 va = *(const float4*)&xv[ks*32 + ((l >> 4) << 3)];
            const float4 vb4 = *(const float4*)&xv[ks*32 + ((l >> 4) << 3) + 4];
            const float vv[8] = {va.x, va.y, va.z, va.w, vb4.x, vb4.y, vb4.z, vb4.w};
            #pragma unroll
            for (int j = 0; j < 8; ++j) {
                mx = fmaxf(mx, u0 * bf2f((u16)kf[0][ks][j]) * vv[j]);
                mx = fmaxf(mx, u1 * bf2f((u16)kf[1][ks][j]) * vv[j]);
            }
        }
    }
    #pragma unroll
    for (int off = 32; off > 0; off >>= 1) mx = fmaxf(mx, __shfl_xor(mx, off));
    if (l == 0) pmax[w] = mx;
    __syncthreads();
    if (tid < 256) {
        ubuf[bh * 256 + tid] = usave[tid];
        vbuf[bh * 256 + tid] = xv[tid];
    }
    if (tid == 0) {
        float m = pmax[0];
        #pragma unroll
        for (int i = 1; i < 8; ++i) m = fmaxf(m, pmax[i]);
        tmaxbuf[bh] = m;
    }
}

// =======================================================================
// K4: per (b,h), 256 threads / 4 waves; thread-per-row P + MFMA PV.
// =======================================================================
__global__ __launch_bounds__(256)
void softpv_kernel(const u16* __restrict__ Kmat, const u16* __restrict__ vbfT,
                   const float* __restrict__ ubuf, const float* __restrict__ vbuf,
                   const float* __restrict__ tmaxbuf, u16* __restrict__ ctxc)
{
    __shared__ u16 Vt[64*256];     // [d][m] bf16, swizzled: slot s holds global slot s^(d&7)
    __shared__ u16 Pl[256*64];     // [n][m-chunk] bf16, swizzled: slot i at i^(n&7)
    __shared__ float vmf[256];
    __shared__ float sinv[256];
    const int bh = blockIdx.x;
    const int b_ = bh / 12, h_ = bh - b_*12;
    const int tid = threadIdx.x;
    const int l = tid & 63, w = tid >> 6;

    // ---- stage Vt (32 KB): 8 issues x (256 thr x 16B); source pre-swizzled
    {
        const char* src = (const char*)(vbfT + (size_t)bh * 16384);
        char* dst = (char*)Vt;
        const int s = l & 31;                      // 16B slot within 512B row
        #pragma unroll
        for (int i = 0; i < 8; ++i) {
            const int d = i*8 + w*2 + (l >> 5);
            gload_lds16(src + d*512 + ((s ^ (d & 7)) << 4), dst + i*4096 + w*1024);
        }
    }
    vmf[tid] = vbuf[bh*256 + tid];
    const float an = ubuf[bh*256 + tid] * (1.0f / tmaxbuf[bh]) * 0.125f;
    const u16* Krow = Kmat + (size_t)bh*65536 + (size_t)tid*256;
    __syncthreads();                               // Vt + vmf resident

    f32x4 acc[4][4];                               // [mi=d-frag][nj=n-frag]
    #pragma unroll
    for (int i = 0; i < 4; ++i)
        #pragma unroll
        for (int j = 0; j < 4; ++j) acc[i][j] = (f32x4){0.f,0.f,0.f,0.f};
    float psum = 0.f;
    char* prow = (char*)Pl + tid*128;
    const int nsw = tid & 7;

    #pragma unroll
    for (int mc = 0; mc < 4; ++mc) {
        // ---- P row chunk: 8 x uint4 K loads, exp, pack, swizzled ds_write
        const uint4* kr = (const uint4*)(Krow + mc*64);
        #pragma unroll
        for (int i = 0; i < 8; ++i) {
            const uint4 raw = kr[i];
            const float4 va = *(const float4*)&vmf[mc*64 + i*8];
            const float4 vbq = *(const float4*)&vmf[mc*64 + i*8 + 4];
            float p[8];
            p[0] = __expf(an * bf2f((u16)(raw.x & 0xffffu)) * va.x);
            p[1] = __expf(an * bf2f((u16)(raw.x >> 16))     * va.y);
            p[2] = __expf(an * bf2f((u16)(raw.y & 0xffffu)) * va.z);
            p[3] = __expf(an * bf2f((u16)(raw.y >> 16))     * va.w);
            p[4] = __expf(an * bf2f((u16)(raw.z & 0xffffu)) * vbq.x);
            p[5] = __expf(an * bf2f((u16)(raw.z >> 16))     * vbq.y);
            p[6] = __expf(an * bf2f((u16)(raw.w & 0xffffu)) * vbq.z);
            p[7] = __expf(an * bf2f((u16)(raw.w >> 16))     * vbq.w);
            const int dj = tid - mc*64 - i*8;      // diagonal override
            if (dj >= 0 && dj < 8) p[dj] = 1.13314845f;   // exp(0.125)
            psum += ((p[0]+p[1]) + (p[2]+p[3])) + ((p[4]+p[5]) + (p[6]+p[7]));
            uint4 pw = make_uint4(pack2bf(p[0],p[1]), pack2bf(p[2],p[3]),
                                  pack2bf(p[4],p[5]), pack2bf(p[6],p[7]));
            *(uint4*)(prow + ((i ^ nsw) << 4)) = pw;
        }
        // ---- MFMA: D[d][n] += Vt[d][m-chunk] * P[n][m-chunk]
        #pragma unroll
        for (int kk = 0; kk < 2; ++kk) {
            bf16x8 afr[4], bfr[4];
            const int kb = kk*64 + ((l >> 4) << 4);
            #pragma unroll
            for (int f = 0; f < 4; ++f) {
                const int d = f*16 + (l & 15);
                afr[f] = *(const bf16x8*)((char*)Vt + d*512 + ((mc*128 + kb) ^ ((d & 7) << 4)));
                const int n = w*64 + f*16 + (l & 15);
                bfr[f] = *(const bf16x8*)((char*)Pl + n*128 + (kb ^ ((n & 7) << 4)));
            }
            #pragma unroll
            for (int mi = 0; mi < 4; ++mi)
                #pragma unroll
                for (int nj = 0; nj < 4; ++nj)
                    acc[mi][nj] = __builtin_amdgcn_mfma_f32_16x16x32_bf16(
                                      afr[mi], bfr[nj], acc[mi][nj], 0, 0, 0);
        }
    }
    sinv[tid] = 1.0f / psum;
    __syncthreads();
    // ---- epilogue: lane col = n, regs rr -> d consecutive
    u16* outp = ctxc + ((size_t)b_*256)*768 + h_*64;
    #pragma unroll
    for (int nj = 0; nj < 4; ++nj) {
        const int n = w*64 + nj*16 + (l & 15);
        const float is = sinv[n];
        #pragma unroll
        for (int mi = 0; mi < 4; ++mi) {
            const int d0 = mi*16 + ((l >> 4) << 2);
            uint2 o = make_uint2(pack2bf(acc[mi][nj][0]*is, acc[mi][nj][1]*is),
                                 pack2bf(acc[mi][nj][2]*is, acc[mi][nj][3]*is));
            *(uint2*)&outp[(size_t)n*768 + d0] = o;
        }
    }
}

// =======================================================================
extern "C" void kernel_launch(void* const* d_in, const int* in_sizes, int n_in,
                              void* d_out, int out_size, void* d_ws, size_t ws_size,
                              hipStream_t stream)
{
    (void)in_sizes; (void)n_in; (void)out_size; (void)ws_size;
    const float* x      = (const float*)d_in[0];
    const float* w_qkv  = (const float*)d_in[1];
    const float* w_proj = (const float*)d_in[2];
    const float* b_proj = (const float*)d_in[3];
    float* out = (float*)d_out;

    char* w = (char*)d_ws;
    // workspace layout (bytes):
    u16*   xbf  = (u16*)  (w);                     //  25,165,824  x bf16 [16384][768]; DEAD after
                                                   //  gemm_qkv -> reused as qnbf [768][256][64]
    u16*   wqv  = (u16*)  (w + 25165824);          //   2,359,296  w q+v rows bf16 [1536][768]
    u16*   wpb  = (u16*)  (w + 27525120);          //   1,179,648  w_proj bf16 [768][768]
    float* qbuf = (float*)(w + 28704768);          //  50,331,648  q fp32 [768][256][64]
    u16*   vbfT = (u16*)  (w + 79036416);          //  25,165,824  v^T bf16 [768][64][256]
    u16*   ctxc = (u16*)  (w + 104202240);         //  25,165,824  ctx bf16 [64][256][768]
    float* ub   = (float*)(w + 129368064);         //     786,432  u [768][256]
    float* vb   = (float*)(w + 130154496);         //     786,432  v [768][256]
    float* tmx  = (float*)(w + 130940928);         //       3,072  tmax [768]
    u16*   Km   = (u16*)  (w + 130944000);         // 100,663,296  K bf16 [768][256][256]
    // total ~231.6 MB
    u16*   qnbf = xbf;                             // alias: x consumed before qn produced

    conv_bf16       <<<dim3(6144),    256, 0, stream>>>(x, xbf, 1572864);
    conv_wqv        <<<dim3(576),     256, 0, stream>>>(w_qkv, wqv);
    conv_bf16       <<<dim3(288),     256, 0, stream>>>(w_proj, wpb, 73728);
    gemm_qkv_mfma   <<<dim3(128, 12), 256, 0, stream>>>(xbf, wqv, qbuf, vbfT);
    normalize_kernel<<<dim3(49152),   256, 0, stream>>>(qbuf, qnbf);
    cost_kernel     <<<dim3(4, 768),  256, 0, stream>>>(qnbf, Km);
    sinkhorn_kernel <<<dim3(768),     512, 0, stream>>>(Km, ub, vb, tmx);
    softpv_kernel   <<<dim3(768),     256, 0, stream>>>(Km, vbfT, ub, vb, tmx, ctxc);
    gemm_proj_mfma  <<<dim3(128, 6),  256, 0, stream>>>(ctxc, wpb, b_proj, out);
}

// Round 7
// 224.940 us; speedup vs baseline: 5.6593x; 1.1010x over previous
//
#include <hip/hip_runtime.h>

typedef unsigned short u16;
typedef unsigned int   u32;
typedef __attribute__((ext_vector_type(8))) short bf16x8;
typedef __attribute__((ext_vector_type(4))) float f32x4;

// ---------- bf16 helpers (manual, RNE) ----------
__device__ __forceinline__ u16 f2bf(float f) {
    u32 u = __float_as_uint(f);
    u += 0x7fffu + ((u >> 16) & 1u);
    return (u16)(u >> 16);
}
__device__ __forceinline__ float bf2f(u16 s) {
    return __uint_as_float(((u32)s) << 16);
}
__device__ __forceinline__ u32 pack2bf(float f0, float f1) {
    return (u32)f2bf(f0) | ((u32)f2bf(f1) << 16);
}

__device__ __forceinline__ void gload_lds16(const void* g, void* l) {
    __builtin_amdgcn_global_load_lds(
        (const __attribute__((address_space(1))) u32*)g,
        (__attribute__((address_space(3))) u32*)l, 16, 0, 0);
}

// =======================================================================
// fp32 -> bf16 converters
// =======================================================================
__global__ __launch_bounds__(256)
void conv_bf16(const float* __restrict__ src, u16* __restrict__ dst, int n8)
{
    const int i = blockIdx.x * 256 + threadIdx.x;   // 8 elements per thread
    if (i < n8) {
        const float4 a = ((const float4*)src)[2*i];
        const float4 b = ((const float4*)src)[2*i + 1];
        ((uint4*)dst)[i] = make_uint4(pack2bf(a.x,a.y), pack2bf(a.z,a.w),
                                      pack2bf(b.x,b.y), pack2bf(b.z,b.w));
    }
}

// w_qkv [2304][768]: keep q rows 0..767 and v rows 1536..2303 -> wqv [1536][768]
__global__ __launch_bounds__(256)
void conv_wqv(const float* __restrict__ w, u16* __restrict__ dst)
{
    const int i = blockIdx.x * 256 + threadIdx.x;   // chunk of 8, 96 chunks/row
    const int row = i / 96;
    const int cc  = (i - row * 96) * 8;
    const int srow = row + (row >= 768 ? 768 : 0);
    const float4 a = *(const float4*)&w[(size_t)srow*768 + cc];
    const float4 b = *(const float4*)&w[(size_t)srow*768 + cc + 4];
    *(uint4*)&dst[(size_t)row*768 + cc] =
        make_uint4(pack2bf(a.x,a.y), pack2bf(a.z,a.w), pack2bf(b.x,b.y), pack2bf(b.z,b.w));
}

// =======================================================================
// Shared MFMA GEMM core: C[128x128] tile, K=768, bf16 A[.,768] x B[.,768]^T.
// BK=64, 4 waves (2x2), 16x16x32 MFMA, global_load_lds + XOR-swizzled LDS.
// =======================================================================
__device__ __forceinline__ void mfma_gemm_core(
    const char* __restrict__ Arow0,   // &A[m0][0] as bytes (row stride 1536)
    const char* __restrict__ Brow0,   // &B[n0][0] as bytes
    u16* As, u16* Bs, const int tid, f32x4 acc[4][4])
{
    const int l  = tid & 63, w = tid >> 6;
    const int wr = w >> 1,  wc = w & 1;
    char* Asb = (char*)As;
    char* Bsb = (char*)Bs;
    const int co = 16 * ((l & 7) ^ (l >> 3));       // swizzled global byte col
    const size_t rstep = (size_t)(l >> 3) * 1536;
    const int rsw = (l & 7) << 4;                   // read-side XOR

    for (int k0 = 0; k0 < 1536; k0 += 128) {        // 12 K-steps of 64 bf16
        #pragma unroll
        for (int i = 0; i < 4; ++i) {
            const int rb = i*32 + w*8;
            gload_lds16(Arow0 + (size_t)rb*1536 + rstep + k0 + co, Asb + i*4096 + w*1024);
            gload_lds16(Brow0 + (size_t)rb*1536 + rstep + k0 + co, Bsb + i*4096 + w*1024);
        }
        __syncthreads();
        bf16x8 af[2][4], bfr[2][4];
        #pragma unroll
        for (int kk = 0; kk < 2; ++kk) {
            const int coff = (kk*64 + ((l >> 4) << 4)) ^ rsw;
            #pragma unroll
            for (int mi = 0; mi < 4; ++mi) {
                const int rowA = wr*64 + mi*16 + (l & 15);
                af[kk][mi]  = *(const bf16x8*)(Asb + rowA*128 + coff);
                const int rowB = wc*64 + mi*16 + (l & 15);
                bfr[kk][mi] = *(const bf16x8*)(Bsb + rowB*128 + coff);
            }
        }
        #pragma unroll
        for (int mi = 0; mi < 4; ++mi)
            #pragma unroll
            for (int nj = 0; nj < 4; ++nj) {
                acc[mi][nj] = __builtin_amdgcn_mfma_f32_16x16x32_bf16(
                                  af[0][mi], bfr[0][nj], acc[mi][nj], 0, 0, 0);
                acc[mi][nj] = __builtin_amdgcn_mfma_f32_16x16x32_bf16(
                                  af[1][mi], bfr[1][nj], acc[mi][nj], 0, 0, 0);
            }
        __syncthreads();
    }
}

// =======================================================================
// K0: q/v projection + FUSED q-normalize. xbf [16384][768], wqv [1536][768].
// bj<6 -> q cols: each wave's 64 cols = one head (h = 2bj+wc); row-norm via
// 16-lane shfl_xor reduce over nj-frags; writes qn bf16 [bh][n][64] direct.
// bj>=6 -> v cols, written TRANSPOSED as vbfT [bh][d][m] bf16.
// =======================================================================
__global__ __launch_bounds__(256)
void gemm_qkv_mfma(const u16* __restrict__ xbf, const u16* __restrict__ wqv,
                   u16* __restrict__ qnbf, u16* __restrict__ vbfT)
{
    __shared__ u16 As[128*64];
    __shared__ u16 Bs[128*64];
    const int m0 = blockIdx.x * 128;
    const int bj = blockIdx.y;
    const int tid = threadIdx.x;
    f32x4 acc[4][4];
    #pragma unroll
    for (int i = 0; i < 4; ++i)
        #pragma unroll
        for (int j = 0; j < 4; ++j) acc[i][j] = (f32x4){0.f,0.f,0.f,0.f};

    mfma_gemm_core((const char*)xbf + (size_t)m0*1536,
                   (const char*)wqv + (size_t)bj*128*1536,
                   As, Bs, tid, acc);

    const int l = tid & 63, w = tid >> 6;
    const int wr = w >> 1, wc = w & 1;
    const int rbase = m0 + wr*64 + ((l >> 4) << 2);
    if (bj < 6) {
        const int h = 2*bj + wc;                   // wave's 64 cols = head h
        #pragma unroll
        for (int mi = 0; mi < 4; ++mi)
            #pragma unroll
            for (int rr = 0; rr < 4; ++rr) {
                float s =      acc[mi][0][rr]*acc[mi][0][rr];
                s = fmaf(acc[mi][1][rr], acc[mi][1][rr], s);
                s = fmaf(acc[mi][2][rr], acc[mi][2][rr], s);
                s = fmaf(acc[mi][3][rr], acc[mi][3][rr], s);
                #pragma unroll
                for (int off = 1; off < 16; off <<= 1) s += __shfl_xor(s, off);
                const float inv = 1.0f / (sqrtf(s) + 1e-8f);
                const int m = rbase + mi*16 + rr;
                const int b_ = m >> 8, n_ = m & 255;
                u16* row = qnbf + ((((size_t)b_*12 + h) << 8) + n_)*64;
                #pragma unroll
                for (int nj = 0; nj < 4; ++nj)
                    row[nj*16 + (l & 15)] = f2bf(acc[mi][nj][rr] * inv);
            }
    } else {
        const int colb = (bj - 6)*128 + wc*64;
        #pragma unroll
        for (int mi = 0; mi < 4; ++mi)
            #pragma unroll
            for (int nj = 0; nj < 4; ++nj) {
                const int col = colb + nj*16 + (l & 15);
                const int h = col >> 6, d = col & 63;
                const int m = rbase + mi*16;        // rows m..m+3 (consecutive)
                const int b_ = m >> 8, n_ = m & 255;
                uint2 o = make_uint2(pack2bf(acc[mi][nj][0], acc[mi][nj][1]),
                                     pack2bf(acc[mi][nj][2], acc[mi][nj][3]));
                *(uint2*)&vbfT[(((size_t)b_*12 + h)*64 + d)*256 + n_] = o;
            }
    }
}

// =======================================================================
// K5: out = ctx @ w_proj^T + b_proj. ctxb [16384][768] bf16, wpb [768][768] bf16.
// =======================================================================
__global__ __launch_bounds__(256)
void gemm_proj_mfma(const u16* __restrict__ ctxb, const u16* __restrict__ wpb,
                    const float* __restrict__ bias, float* __restrict__ out)
{
    __shared__ u16 As[128*64];
    __shared__ u16 Bs[128*64];
    const int m0 = blockIdx.x * 128;
    const int n0 = blockIdx.y * 128;
    const int tid = threadIdx.x;
    f32x4 acc[4][4];
    #pragma unroll
    for (int i = 0; i < 4; ++i)
        #pragma unroll
        for (int j = 0; j < 4; ++j) acc[i][j] = (f32x4){0.f,0.f,0.f,0.f};

    mfma_gemm_core((const char*)ctxb + (size_t)m0*1536,
                   (const char*)wpb + (size_t)n0*1536,
                   As, Bs, tid, acc);

    const int l = tid & 63, w = tid >> 6;
    const int wr = w >> 1, wc = w & 1;
    const int rbase = m0 + wr*64 + ((l >> 4) << 2);
    #pragma unroll
    for (int mi = 0; mi < 4; ++mi)
        #pragma unroll
        for (int nj = 0; nj < 4; ++nj) {
            const int col = n0 + wc*64 + nj*16 + (l & 15);
            const float bv = bias[col];
            #pragma unroll
            for (int rr = 0; rr < 4; ++rr) {
                const int m = rbase + mi*16 + rr;
                out[(size_t)m*768 + col] = acc[mi][nj][rr] + bv;
            }
        }
}

// =======================================================================
// K2: K[n][m] = exp(10*cos(n,m) - 10) off-diag, 0 on diag. bf16 out.
// MFMA on qn bf16 tiles, XOR-swizzled LDS, fused exp epilogue.
// =======================================================================
__global__ __launch_bounds__(256)
void cost_kernel(const u16* __restrict__ qnbf, u16* __restrict__ Kmat)
{
    __shared__ u16 Qa[128*64];     // [row][64 k] bf16, slot s holds global slot s^(row&7)
    __shared__ u16 Qb[128*64];
    const int bh = blockIdx.y;
    const int tr = (blockIdx.x >> 1) * 128;
    const int tc = (blockIdx.x & 1) * 128;
    const char* qb = (const char*)(qnbf + (size_t)bh * 16384);
    const int tid = threadIdx.x;
    const int l = tid & 63, w = tid >> 6;
    const int wr = w >> 1, wc = w & 1;

    // ---- stage both tiles: 4 issues/wave/array; rows 8*(i*4+w)+(l>>3)
    {
        const int co = ((l & 7) ^ (l >> 3)) << 4;   // inverse-swizzled source slot
        const int rl = l >> 3;
        #pragma unroll
        for (int i = 0; i < 4; ++i) {
            const int ch = i*4 + w;                 // chunk 0..15
            gload_lds16(qb + (size_t)(tr + ch*8 + rl)*128 + co, (char*)Qa + ch*1024);
            gload_lds16(qb + (size_t)(tc + ch*8 + rl)*128 + co, (char*)Qb + ch*1024);
        }
    }
    __syncthreads();

    f32x4 acc[4][4];
    #pragma unroll
    for (int i = 0; i < 4; ++i)
        #pragma unroll
        for (int j = 0; j < 4; ++j) acc[i][j] = (f32x4){0.f,0.f,0.f,0.f};

    bf16x8 af[2][4], bfr[2][4];
    #pragma unroll
    for (int kk = 0; kk < 2; ++kk) {
        const int kb = kk*64 + ((l >> 4) << 4);
        #pragma unroll
        for (int f = 0; f < 4; ++f) {
            const int ra = wr*64 + f*16 + (l & 15);
            af[kk][f]  = *(const bf16x8*)((char*)Qa + ra*128 + (kb ^ ((ra & 7) << 4)));
            const int rb = wc*64 + f*16 + (l & 15);
            bfr[kk][f] = *(const bf16x8*)((char*)Qb + rb*128 + (kb ^ ((rb & 7) << 4)));
        }
    }
    #pragma unroll
    for (int mi = 0; mi < 4; ++mi)
        #pragma unroll
        for (int nj = 0; nj < 4; ++nj) {
            acc[mi][nj] = __builtin_amdgcn_mfma_f32_16x16x32_bf16(
                              af[0][mi], bfr[0][nj], acc[mi][nj], 0, 0, 0);
            acc[mi][nj] = __builtin_amdgcn_mfma_f32_16x16x32_bf16(
                              af[1][mi], bfr[1][nj], acc[mi][nj], 0, 0, 0);
        }

    // ---- epilogue: exp(10*s - 10), diag -> 0, bf16 store
    u16* Kb = Kmat + (size_t)bh * 65536;
    #pragma unroll
    for (int mi = 0; mi < 4; ++mi)
        #pragma unroll
        for (int nj = 0; nj < 4; ++nj) {
            const int gr0 = tr + wr*64 + mi*16 + ((l >> 4) << 2);
            const int gc  = tc + wc*64 + nj*16 + (l & 15);
            #pragma unroll
            for (int rr = 0; rr < 4; ++rr) {
                const int gr = gr0 + rr;
                const float s = acc[mi][nj][rr];
                const float km = (gr == gc) ? 0.f : __expf(fmaf(10.f, s, -10.f));
                Kb[(size_t)gr * 256 + gc] = f2bf(km);
            }
        }
}

// =======================================================================
// K3: Sinkhorn with K held in MFMA A-frags (VGPRs), matvec on matrix cores.
// =======================================================================
__global__ __launch_bounds__(512, 4)
void sinkhorn_kernel(const u16* __restrict__ Kmat, float* __restrict__ ubuf,
                     float* __restrict__ vbuf, float* __restrict__ tmaxbuf)
{
    __shared__ __align__(16) float ys[256];
    __shared__ __align__(16) float xv[256];
    __shared__ __align__(16) float usave[256];
    __shared__ __align__(16) u16   xbf[256];
    __shared__ float pmax[8];
    const int bh  = blockIdx.x;
    const int tid = threadIdx.x;
    const int l = tid & 63, w = tid >> 6;
    const int rowb = w * 32;
    const char* Kg = (const char*)(Kmat + (size_t)bh * 65536);

    // ---- K frags: lane l holds K[rowb + t*16 + (l&15)][ks*32 + (l>>4)*8 + j]
    bf16x8 kf[2][8];
    {
        const char* kb0 = Kg + (size_t)(rowb + (l & 15)) * 512 + ((l >> 4) << 4);
        #pragma unroll
        for (int t = 0; t < 2; ++t)
            #pragma unroll
            for (int ks = 0; ks < 8; ++ks)
                kf[t][ks] = *(const bf16x8*)(kb0 + t*8192 + ks*64);
    }
    if (tid < 256) { xv[tid] = 1.0f; xbf[tid] = 0x3f80; }   // bf16(1.0)
    __syncthreads();

    for (int it = 0; it < 20; ++it) {
        f32x4 a0 = {0.f,0.f,0.f,0.f}, a1 = {0.f,0.f,0.f,0.f};
        #pragma unroll
        for (int ks = 0; ks < 8; ++ks) {
            const bf16x8 xf = *(const bf16x8*)((const char*)xbf + ks*64 + ((l >> 4) << 4));
            a0 = __builtin_amdgcn_mfma_f32_16x16x32_bf16(kf[0][ks], xf, a0, 0, 0, 0);
            a1 = __builtin_amdgcn_mfma_f32_16x16x32_bf16(kf[1][ks], xf, a1, 0, 0, 0);
        }
        if ((l & 15) == 0) {                 // 4 lanes publish 2x4 rows each
            const int r0 = rowb + ((l >> 4) << 2);
            *(float4*)&ys[r0]      = make_float4(a0[0], a0[1], a0[2], a0[3]);
            *(float4*)&ys[r0 + 16] = make_float4(a1[0], a1[1], a1[2], a1[3]);
        }
        __syncthreads();
        if (tid < 256) {
            const float xn = 0.00390625f / ys[tid];   // (1/256)/y
            if (it == 18) usave[tid] = xn;            // u after 19th half-step
            xv[tid]  = xn;
            xbf[tid] = f2bf(xn);
        }
        __syncthreads();
    }

    // ---- Tmax = max u[n] K[n][m] v[m]; frags cover all (row,k) pairs once
    float mx = 0.f;
    {
        const float u0 = usave[rowb + (l & 15)];
        const float u1 = usave[rowb + 16 + (l & 15)];
        #pragma unroll
        for (int ks = 0; ks < 8; ++ks) {
            const float4 va = *(const float4*)&xv[ks*32 + ((l >> 4) << 3)];
            const float4 vb4 = *(const float4*)&xv[ks*32 + ((l >> 4) << 3) + 4];
            const float vv[8] = {va.x, va.y, va.z, va.w, vb4.x, vb4.y, vb4.z, vb4.w};
            #pragma unroll
            for (int j = 0; j < 8; ++j) {
                mx = fmaxf(mx, u0 * bf2f((u16)kf[0][ks][j]) * vv[j]);
                mx = fmaxf(mx, u1 * bf2f((u16)kf[1][ks][j]) * vv[j]);
            }
        }
    }
    #pragma unroll
    for (int off = 32; off > 0; off >>= 1) mx = fmaxf(mx, __shfl_xor(mx, off));
    if (l == 0) pmax[w] = mx;
    __syncthreads();
    if (tid < 256) {
        ubuf[bh * 256 + tid] = usave[tid];
        vbuf[bh * 256 + tid] = xv[tid];
    }
    if (tid == 0) {
        float m = pmax[0];
        #pragma unroll
        for (int i = 1; i < 8; ++i) m = fmaxf(m, pmax[i]);
        tmaxbuf[bh] = m;
    }
}

// =======================================================================
// K4: per (b,h), 256 threads / 4 waves; thread-per-row P + MFMA PV.
// =======================================================================
__global__ __launch_bounds__(256)
void softpv_kernel(const u16* __restrict__ Kmat, const u16* __restrict__ vbfT,
                   const float* __restrict__ ubuf, const float* __restrict__ vbuf,
                   const float* __restrict__ tmaxbuf, u16* __restrict__ ctxc)
{
    __shared__ u16 Vt[64*256];     // [d][m] bf16, swizzled: slot s holds global slot s^(d&7)
    __shared__ u16 Pl[256*64];     // [n][m-chunk] bf16, swizzled: slot i at i^(n&7)
    __shared__ float vmf[256];
    __shared__ float sinv[256];
    const int bh = blockIdx.x;
    const int b_ = bh / 12, h_ = bh - b_*12;
    const int tid = threadIdx.x;
    const int l = tid & 63, w = tid >> 6;

    // ---- stage Vt (32 KB): 8 issues x (256 thr x 16B); source pre-swizzled
    {
        const char* src = (const char*)(vbfT + (size_t)bh * 16384);
        char* dst = (char*)Vt;
        const int s = l & 31;                      // 16B slot within 512B row
        #pragma unroll
        for (int i = 0; i < 8; ++i) {
            const int d = i*8 + w*2 + (l >> 5);
            gload_lds16(src + d*512 + ((s ^ (d & 7)) << 4), dst + i*4096 + w*1024);
        }
    }
    vmf[tid] = vbuf[bh*256 + tid];
    const float an = ubuf[bh*256 + tid] * (1.0f / tmaxbuf[bh]) * 0.125f;
    const u16* Krow = Kmat + (size_t)bh*65536 + (size_t)tid*256;
    __syncthreads();                               // Vt + vmf resident

    f32x4 acc[4][4];                               // [mi=d-frag][nj=n-frag]
    #pragma unroll
    for (int i = 0; i < 4; ++i)
        #pragma unroll
        for (int j = 0; j < 4; ++j) acc[i][j] = (f32x4){0.f,0.f,0.f,0.f};
    float psum = 0.f;
    char* prow = (char*)Pl + tid*128;
    const int nsw = tid & 7;

    #pragma unroll
    for (int mc = 0; mc < 4; ++mc) {
        // ---- P row chunk: 8 x uint4 K loads, exp, pack, swizzled ds_write
        const uint4* kr = (const uint4*)(Krow + mc*64);
        #pragma unroll
        for (int i = 0; i < 8; ++i) {
            const uint4 raw = kr[i];
            const float4 va = *(const float4*)&vmf[mc*64 + i*8];
            const float4 vbq = *(const float4*)&vmf[mc*64 + i*8 + 4];
            float p[8];
            p[0] = __expf(an * bf2f((u16)(raw.x & 0xffffu)) * va.x);
            p[1] = __expf(an * bf2f((u16)(raw.x >> 16))     * va.y);
            p[2] = __expf(an * bf2f((u16)(raw.y & 0xffffu)) * va.z);
            p[3] = __expf(an * bf2f((u16)(raw.y >> 16))     * va.w);
            p[4] = __expf(an * bf2f((u16)(raw.z & 0xffffu)) * vbq.x);
            p[5] = __expf(an * bf2f((u16)(raw.z >> 16))     * vbq.y);
            p[6] = __expf(an * bf2f((u16)(raw.w & 0xffffu)) * vbq.z);
            p[7] = __expf(an * bf2f((u16)(raw.w >> 16))     * vbq.w);
            const int dj = tid - mc*64 - i*8;      // diagonal override
            if (dj >= 0 && dj < 8) p[dj] = 1.13314845f;   // exp(0.125)
            psum += ((p[0]+p[1]) + (p[2]+p[3])) + ((p[4]+p[5]) + (p[6]+p[7]));
            uint4 pw = make_uint4(pack2bf(p[0],p[1]), pack2bf(p[2],p[3]),
                                  pack2bf(p[4],p[5]), pack2bf(p[6],p[7]));
            *(uint4*)(prow + ((i ^ nsw) << 4)) = pw;
        }
        // ---- MFMA: D[d][n] += Vt[d][m-chunk] * P[n][m-chunk]
        #pragma unroll
        for (int kk = 0; kk < 2; ++kk) {
            bf16x8 afr[4], bfr[4];
            const int kb = kk*64 + ((l >> 4) << 4);
            #pragma unroll
            for (int f = 0; f < 4; ++f) {
                const int d = f*16 + (l & 15);
                afr[f] = *(const bf16x8*)((char*)Vt + d*512 + ((mc*128 + kb) ^ ((d & 7) << 4)));
                const int n = w*64 + f*16 + (l & 15);
                bfr[f] = *(const bf16x8*)((char*)Pl + n*128 + (kb ^ ((n & 7) << 4)));
            }
            #pragma unroll
            for (int mi = 0; mi < 4; ++mi)
                #pragma unroll
                for (int nj = 0; nj < 4; ++nj)
                    acc[mi][nj] = __builtin_amdgcn_mfma_f32_16x16x32_bf16(
                                      afr[mi], bfr[nj], acc[mi][nj], 0, 0, 0);
        }
    }
    sinv[tid] = 1.0f / psum;
    __syncthreads();
    // ---- epilogue: lane col = n, regs rr -> d consecutive
    u16* outp = ctxc + ((size_t)b_*256)*768 + h_*64;
    #pragma unroll
    for (int nj = 0; nj < 4; ++nj) {
        const int n = w*64 + nj*16 + (l & 15);
        const float is = sinv[n];
        #pragma unroll
        for (int mi = 0; mi < 4; ++mi) {
            const int d0 = mi*16 + ((l >> 4) << 2);
            uint2 o = make_uint2(pack2bf(acc[mi][nj][0]*is, acc[mi][nj][1]*is),
                                 pack2bf(acc[mi][nj][2]*is, acc[mi][nj][3]*is));
            *(uint2*)&outp[(size_t)n*768 + d0] = o;
        }
    }
}

// =======================================================================
extern "C" void kernel_launch(void* const* d_in, const int* in_sizes, int n_in,
                              void* d_out, int out_size, void* d_ws, size_t ws_size,
                              hipStream_t stream)
{
    (void)in_sizes; (void)n_in; (void)out_size; (void)ws_size;
    const float* x      = (const float*)d_in[0];
    const float* w_qkv  = (const float*)d_in[1];
    const float* w_proj = (const float*)d_in[2];
    const float* b_proj = (const float*)d_in[3];
    float* out = (float*)d_out;

    char* w = (char*)d_ws;
    // workspace layout (bytes):
    u16*   xbf  = (u16*)  (w);                     //  25,165,824  x bf16 [16384][768]
    u16*   wqv  = (u16*)  (w + 25165824);          //   2,359,296  w q+v rows bf16 [1536][768]
    u16*   wpb  = (u16*)  (w + 27525120);          //   1,179,648  w_proj bf16 [768][768]
    u16*   qnbf = (u16*)  (w + 28704768);          //  25,165,824  qn bf16 [768][256][64]
                                                   //  (+25 MB spare, old qbuf region)
    u16*   vbfT = (u16*)  (w + 79036416);          //  25,165,824  v^T bf16 [768][64][256]
    u16*   ctxc = (u16*)  (w + 104202240);         //  25,165,824  ctx bf16 [64][256][768]
    float* ub   = (float*)(w + 129368064);         //     786,432  u [768][256]
    float* vb   = (float*)(w + 130154496);         //     786,432  v [768][256]
    float* tmx  = (float*)(w + 130940928);         //       3,072  tmax [768]
    u16*   Km   = (u16*)  (w + 130944000);         // 100,663,296  K bf16 [768][256][256]
    // total ~231.6 MB

    conv_bf16       <<<dim3(6144),    256, 0, stream>>>(x, xbf, 1572864);
    conv_wqv        <<<dim3(576),     256, 0, stream>>>(w_qkv, wqv);
    conv_bf16       <<<dim3(288),     256, 0, stream>>>(w_proj, wpb, 73728);
    gemm_qkv_mfma   <<<dim3(128, 12), 256, 0, stream>>>(xbf, wqv, qnbf, vbfT);
    cost_kernel     <<<dim3(4, 768),  256, 0, stream>>>(qnbf, Km);
    sinkhorn_kernel <<<dim3(768),     512, 0, stream>>>(Km, ub, vb, tmx);
    softpv_kernel   <<<dim3(768),     256, 0, stream>>>(Km, vbfT, ub, vb, tmx, ctxc);
    gemm_proj_mfma  <<<dim3(128, 6),  256, 0, stream>>>(ctxc, wpb, b_proj, out);
}